// Round 14
// baseline (137.717 us; speedup 1.0000x reference)
//
#include <hip/hip_runtime.h>

// S4 (SSSD) layer: L=2048, B=16, H=256, N2=32. Output f32.
// R14: (1) k2 at 1024 threads (was 256; 1-block/CU latency-bound -> 4x shorter
// critical path); (2) k4 __launch_bounds__(256,4) to lift occupancy to 4
// blocks/CU; (3) k56 epilogue residual-u staged through LDS (aliasing the
// dead yt/Wl region) instead of 4x64B scattered global reads.

#define PI_F 3.14159265358979323846f
#define LP(i) ((i) + ((i) >> 4))    // LDS pad for k2's fft_fused

typedef __attribute__((ext_vector_type(8))) short bf16x8;
typedef __attribute__((ext_vector_type(4))) float f32x4;

__device__ __forceinline__ float2 cmulf(float2 a, float2 b) {
    return make_float2(a.x*b.x - a.y*b.y, a.x*b.y + a.y*b.x);
}
__device__ __forceinline__ unsigned short f2bf(float f) {
    unsigned int u = __float_as_uint(f);
    u += 0x7fffu + ((u >> 16) & 1u);
    return (unsigned short)(u >> 16);
}

// ---------------- 16-pt register FFT, compile-time twiddles -----------------
template<int SGN>
__device__ __forceinline__ void fft16(float2 v[16]) {
    float2 tsw;
#define SW(i,j) { tsw = v[i]; v[i] = v[j]; v[j] = tsw; }
    SW(1,8) SW(2,4) SW(3,12) SW(5,10) SW(7,14) SW(11,13)
#undef SW
    const float C8[8] = {1.f, 0.92387953251f, 0.70710678119f, 0.38268343236f,
                         0.f, -0.38268343236f, -0.70710678119f, -0.92387953251f};
    const float S8[8] = {0.f, 0.38268343236f, 0.70710678119f, 0.92387953251f,
                         1.f, 0.92387953251f, 0.70710678119f, 0.38268343236f};
    #pragma unroll
    for (int s = 0; s < 4; ++s) {
        const int Ns = 1 << s;
        #pragma unroll
        for (int j = 0; j < 8; ++j) {
            const int k  = j & (Ns - 1);
            const int i0 = ((j >> s) << (s + 1)) | k;
            const int i1 = i0 + Ns;
            const int ti = k << (3 - s);
            const float cs = C8[ti];
            const float sn = (SGN < 0) ? -S8[ti] : S8[ti];
            float2 a = v[i0], b = v[i1];
            float2 t = make_float2(cs*b.x - sn*b.y, cs*b.y + sn*b.x);
            v[i0] = make_float2(a.x + t.x, a.y + t.y);
            v[i1] = make_float2(a.x - t.x, a.y - t.y);
        }
    }
}

// ------------- 4096-pt FFT: 3 phases of fft16, 2 LDS transposes -------------
template<int SGN>
__device__ __forceinline__ void fft4096p(float2 v[16], float2* lds, int t) {
    fft16<SGN>(v);
    float s1, c1;
    __sincosf((float)SGN * (2.0f * PI_F / 4096.0f) * (float)t, &s1, &c1);
    float2 w1 = make_float2(c1, s1), cur = make_float2(1.f, 0.f);
    #pragma unroll
    for (int k = 1; k < 16; ++k) { cur = cmulf(cur, w1); v[k] = cmulf(v[k], cur); }
    __syncthreads();
    #pragma unroll
    for (int k = 0; k < 16; ++k) lds[t * 17 + k] = v[k];
    __syncthreads();
    const int k1 = t & 15, m2 = t >> 4;
    #pragma unroll
    for (int m1 = 0; m1 < 16; ++m1) v[m1] = lds[(m1 * 16 + m2) * 17 + k1];
    fft16<SGN>(v);
    float s2, c2;
    __sincosf((float)SGN * (2.0f * PI_F / 256.0f) * (float)m2, &s2, &c2);
    float2 w2 = make_float2(c2, s2); cur = make_float2(1.f, 0.f);
    #pragma unroll
    for (int j = 1; j < 16; ++j) { cur = cmulf(cur, w2); v[j] = cmulf(v[j], cur); }
    __syncthreads();
    #pragma unroll
    for (int j = 0; j < 16; ++j) lds[m2 * 273 + j * 17 + k1] = v[j];
    __syncthreads();
    #pragma unroll
    for (int m = 0; m < 16; ++m) v[m] = lds[m * 273 + (t >> 4) * 17 + k1];
    fft16<SGN>(v);
}

// -------- in-LDS fused double-stage FFT (k2; nthr-parameterized) ------------
template<int SGN>
__device__ __forceinline__ void fft_fused(float2* A, int N, int logN,
                                          int tid, int nthr) {
    __syncthreads();
    for (int j = tid; j < N; j += nthr) {
        int r = (int)(__brev((unsigned)j) >> (32 - logN));
        if (r > j) { float2 t = A[LP(j)]; A[LP(j)] = A[LP(r)]; A[LP(r)] = t; }
    }
    __syncthreads();
    int s = 0;
    if (logN & 1) {
        for (int j = tid; j < (N >> 1); j += nthr) {
            int i0 = 2 * j;
            float2 a = A[LP(i0)], b = A[LP(i0 + 1)];
            A[LP(i0)]     = make_float2(a.x + b.x, a.y + b.y);
            A[LP(i0 + 1)] = make_float2(a.x - b.x, a.y - b.y);
        }
        __syncthreads();
        s = 1;
    }
    for (; s < logN; s += 2) {
        const int Ns = 1 << s;
        for (int g = tid; g < (N >> 2); g += nthr) {
            int k = g & (Ns - 1);
            int base = ((g >> s) << (s + 2)) | k;
            float2 a0 = A[LP(base)];
            float2 a1 = A[LP(base + Ns)];
            float2 a2 = A[LP(base + 2*Ns)];
            float2 a3 = A[LP(base + 3*Ns)];
            float ang1 = (float)SGN * PI_F * (float)k / (float)Ns;
            float sn1, cs1; __sincosf(ang1, &sn1, &cs1);
            float2 t = make_float2(cs1*a1.x - sn1*a1.y, cs1*a1.y + sn1*a1.x);
            float2 b0 = make_float2(a0.x + t.x, a0.y + t.y);
            float2 b1 = make_float2(a0.x - t.x, a0.y - t.y);
            t = make_float2(cs1*a3.x - sn1*a3.y, cs1*a3.y + sn1*a3.x);
            float2 b2 = make_float2(a2.x + t.x, a2.y + t.y);
            float2 b3 = make_float2(a2.x - t.x, a2.y - t.y);
            float ang2 = (float)SGN * PI_F * (float)k / (float)(2 * Ns);
            float sn2, cs2; __sincosf(ang2, &sn2, &cs2);
            t = make_float2(cs2*b2.x - sn2*b2.y, cs2*b2.y + sn2*b2.x);
            A[LP(base)]        = make_float2(b0.x + t.x, b0.y + t.y);
            A[LP(base + 2*Ns)] = make_float2(b0.x - t.x, b0.y - t.y);
            float c2p, s2p;
            if (SGN < 0) { c2p = sn2; s2p = -cs2; } else { c2p = -sn2; s2p = cs2; }
            t = make_float2(c2p*b3.x - s2p*b3.y, c2p*b3.y + s2p*b3.x);
            A[LP(base + Ns)]   = make_float2(b1.x + t.x, b1.y + t.y);
            A[LP(base + 3*Ns)] = make_float2(b1.x - t.x, b1.y - t.y);
        }
        __syncthreads();
    }
}

// ---------------- K0: convert W [512][256] f32 -> bf16 (row-major) ----------
__global__ void k0_convW(const float* __restrict__ W, unsigned short* __restrict__ Wb)
{
    int i = blockIdx.x * 256 + threadIdx.x;
    if (i < 512 * 256) Wb[i] = f2bf(W[i]);
}

// ---------------- K1: NPLR kernel generation (f32, rcp + packed LDS) --------
__global__ __launch_bounds__(256) void k1_kergen(const float* __restrict__ log_dt,
                          const float* __restrict__ wlr, const float* __restrict__ wim,
                          const float* __restrict__ Pre, const float* __restrict__ Pim,
                          const float* __restrict__ Bre, const float* __restrict__ Bim,
                          const float* __restrict__ Cre, const float* __restrict__ Cim,
                          float2* __restrict__ kf_out)
{
    __shared__ float4 T0[32], T1[32], T2[32], T3[32];
    int h = blockIdx.x;
    int tid = threadIdx.x;
    float dt = expf(log_dt[h]);
    if (tid < 32) {
        int i = h * 32 + tid;
        float wre = -expf(wlr[i]) * dt;
        float wi  = wim[i] * dt;
        float2 B  = make_float2(Bre[i], Bim[i]);
        float2 P  = make_float2(Pre[i], Pim[i]);
        float2 C0 = make_float2(Cre[i], Cim[i]);
        float2 C1 = make_float2(Cre[8192 + i], Cim[8192 + i]);
        float2 Pc = make_float2(P.x, -P.y);
        float2 v00 = cmulf(B, C0), v01 = cmulf(B, C1), v02 = cmulf(B, Pc);
        float2 v10 = cmulf(P, C0), v11 = cmulf(P, C1), v12 = cmulf(P, Pc);
        T0[tid] = make_float4(wre, wi, v00.x, v00.y);
        T1[tid] = make_float4(v01.x, v01.y, v02.x, v02.y);
        T2[tid] = make_float4(v10.x, v10.y, v11.x, v11.y);
        T3[tid] = make_float4(v12.x, v12.y, 0.f, 0.f);
    }
    __syncthreads();
    int f = blockIdx.y * 256 + tid;
    if (f > 1024) return;
    float ang = -(2.0f * PI_F / 2048.0f) * (float)f;
    float sn, cs;
    sincosf(ang, &sn, &cs);
    float2 onep = make_float2(1.0f + cs, sn);
    float invo = __builtin_amdgcn_rcpf(onep.x * onep.x + onep.y * onep.y);
    float2 oinv = make_float2(onep.x * invo, -onep.y * invo);
    float2 z = cmulf(make_float2(2.0f * (1.0f - cs), -2.0f * sn), oinv);
    float2 r00 = {0,0}, r01 = {0,0}, r02 = {0,0};
    float2 r10 = {0,0}, r11 = {0,0}, r12 = {0,0};
    #pragma unroll 4
    for (int n = 0; n < 32; ++n) {
        float4 a  = T0[n];
        float4 bq = T1[n];
        float4 cq = T2[n];
        float4 dq = T3[n];
        float zx  = z.x - a.x;
        float d1y = z.y - a.y;
        float d2y = z.y + a.y;
        float inv1 = __builtin_amdgcn_rcpf(zx * zx + d1y * d1y);
        float inv2 = __builtin_amdgcn_rcpf(zx * zx + d2y * d2y);
        float sx = zx * (inv1 + inv2);
        float dx = zx * (inv1 - inv2);
        float sy = -(d1y * inv1 + d2y * inv2);
        float dy = d1y * inv1 - d2y * inv2;
        r00.x += a.z*sx + a.w*dy;  r00.y += a.z*sy + a.w*dx;
        r01.x += bq.x*sx + bq.y*dy; r01.y += bq.x*sy + bq.y*dx;
        r02.x += bq.z*sx + bq.w*dy; r02.y += bq.z*sy + bq.w*dx;
        r10.x += cq.x*sx + cq.y*dy; r10.y += cq.x*sy + cq.y*dx;
        r11.x += cq.z*sx + cq.w*dy; r11.y += cq.z*sy + cq.w*dx;
        r12.x += dq.x*sx + dq.y*dy; r12.y += dq.x*sy + dq.y*dx;
    }
    r00.x *= dt; r00.y *= dt; r01.x *= dt; r01.y *= dt; r02.x *= dt; r02.y *= dt;
    r10.x *= dt; r10.y *= dt; r11.x *= dt; r11.y *= dt; r12.x *= dt; r12.y *= dt;
    float2 den = make_float2(1.0f + r12.x, r12.y);
    float invd = __builtin_amdgcn_rcpf(den.x * den.x + den.y * den.y);
    float2 idn = make_float2(den.x * invd, -den.y * invd);
    float2 fac = make_float2(2.0f * oinv.x, 2.0f * oinv.y);
    float2 t0 = cmulf(cmulf(r02, r10), idn);
    float2 k0 = cmulf(make_float2(r00.x - t0.x, r00.y - t0.y), fac);
    float2 t1 = cmulf(cmulf(r02, r11), idn);
    float2 k1 = cmulf(make_float2(r01.x - t1.x, r01.y - t1.y), fac);
    kf_out[(size_t)h * 1025 + f]         = k0;
    kf_out[(size_t)(256 + h) * 1025 + f] = k1;
}

// ---------------- K2: packed irfft(ch0,ch1) -> kk -> fft4096 -> kf ----------
// 1024 threads: 1 block/CU, 16 waves -> 4x shorter barrier-to-barrier path.
__global__ __launch_bounds__(1024) void k2_kernelfft(const float2* __restrict__ kfin,
                                                     float2* __restrict__ kfout)
{
    __shared__ float2 A2[2176];
    __shared__ float2 A4[4352];
    int h = blockIdx.x, tid = threadIdx.x;
    const int NT = 1024;
    const float2* s0 = kfin + (size_t)h * 1025;
    const float2* s1 = kfin + (size_t)(256 + h) * 1025;
    for (int j = tid; j < 2048; j += NT) {
        float2 q0, q1;
        if (j == 0)          { q0 = s0[0];    q0.y = 0.0f; q1 = s1[0];    q1.y = 0.0f; }
        else if (j < 1024)   { q0 = s0[j];                 q1 = s1[j]; }
        else if (j == 1024)  { q0 = s0[1024]; q0.y = 0.0f; q1 = s1[1024]; q1.y = 0.0f; }
        else { float2 t0 = s0[2048 - j], t1 = s1[2048 - j];
               q0 = make_float2(t0.x, -t0.y); q1 = make_float2(t1.x, -t1.y); }
        A2[LP(j)] = make_float2(q0.x - q1.y, q0.y + q1.x);   // E0 + i*E1
    }
    fft_fused<+1>(A2, 2048, 11, tid, NT);
    const float scl = 1.0f / 2048.0f;
    for (int j = tid; j < 2048; j += NT) {
        float2 v = A2[LP(j)];
        A4[LP(j)]        = make_float2(v.x * scl, 0.0f);
        A4[LP(4095 - j)] = make_float2(v.y * scl, 0.0f);
    }
    fft_fused<-1>(A4, 4096, 12, tid, NT);
    for (int F = tid; F <= 2048; F += NT)
        kfout[(size_t)h * 2049 + F] = A4[LP(F)];
}

// ---------------- K3: transpose x (2048 x 4096) -> u (4096 x 2048) ----------
__global__ void k3_transpose(const float* __restrict__ x, float* __restrict__ u)
{
    __shared__ float tile[32][33];
    int p0 = blockIdx.x * 32;
    int l0 = blockIdx.y * 32;
    int tx = threadIdx.x, ty = threadIdx.y;
    for (int i = ty; i < 32; i += 8)
        tile[i][tx] = x[(size_t)(l0 + i) * 4096 + p0 + tx];
    __syncthreads();
    for (int i = ty; i < 32; i += 8)
        u[(size_t)(p0 + i) * 2048 + l0 + tx] = tile[tx][i];
}

// ---------------- K4: pair-packed conv via register radix-16 FFT ------------
__global__ __launch_bounds__(256, 4) void k4_conv(const float* __restrict__ u,
        const float2* __restrict__ kf, const float* __restrict__ Dp,
        unsigned short* __restrict__ ygb)
{
    __shared__ float2 lds[4366];
    int h  = blockIdx.x & 255;
    int bp = blockIdx.x >> 8;
    int t  = threadIdx.x;
    const float* u0 = u + (size_t)((2*bp)   * 256 + h) * 2048;
    const float* u1 = u + (size_t)((2*bp+1) * 256 + h) * 2048;
    float2 v[16], us[8];
    #pragma unroll
    for (int n1 = 0; n1 < 8; ++n1) {
        int j = n1 * 256 + t;
        us[n1] = make_float2(u0[j], u1[j]);
        v[n1] = us[n1];
        v[n1 + 8] = make_float2(0.f, 0.f);
    }
    fft4096p<-1>(v, lds, t);
    const float2* kfh = kf + (size_t)h * 2049;
    #pragma unroll
    for (int j2 = 0; j2 < 16; ++j2) {
        int f = t + 256 * j2;
        float2 K;
        if (f <= 2048) K = kfh[f];
        else { float2 q = kfh[4096 - f]; K = make_float2(q.x, -q.y); }
        v[j2] = cmulf(v[j2], K);
    }
    fft4096p<+1>(v, lds, t);
    float d = Dp[h];
    unsigned short* o0 = ygb + (size_t)((2*bp)   * 256 + h) * 2048;
    unsigned short* o1 = ygb + (size_t)((2*bp+1) * 256 + h) * 2048;
    const float iscl = 1.0f / 4096.0f;
    #pragma unroll
    for (int j2 = 0; j2 < 8; ++j2) {
        int l = t + 256 * j2;
        float y0 = v[j2].x * iscl + d * us[j2].x;
        float y1 = v[j2].y * iscl + d * us[j2].y;
        o0[l] = f2bf(0.5f * y0 * (1.0f + erff(y0 * 0.70710678118654752f)));
        o1[l] = f2bf(0.5f * y1 * (1.0f + erff(y1 * 0.70710678118654752f)));
    }
}

// ---------------- K56: MFMA GEMM + GLU + residual + LayerNorm + store -------
// smem blob aliased: [yt | Wl] during GEMM, uS[256][65] f32 during epilogue.
__global__ __launch_bounds__(256, 2) void k56_gemm_glu_ln(const unsigned short* __restrict__ ygb,
        const unsigned short* __restrict__ Wb, const float* __restrict__ bout,
        const float* __restrict__ u, const float* __restrict__ gamma,
        const float* __restrict__ beta, float* __restrict__ out)
{
    __shared__ __align__(16) char smem[67584];   // 2 x 64 x 264 shorts
    short (*yt)[264] = (short(*)[264])smem;
    short (*Wl)[264] = (short(*)[264])(smem + 33792);
    float (*uS)[65]  = (float(*)[65])smem;       // 256*65*4 = 66560 <= 67584
    __shared__ float bo[512];
    __shared__ float gb2[512];
    int b  = blockIdx.y;
    int l0 = blockIdx.x * 64;
    int tid = threadIdx.x;
    int lane = tid & 63, w = tid >> 6;
    int cc = lane & 15, gg = lane >> 4;
    bo[tid] = bout[tid]; bo[tid + 256] = bout[tid + 256];
    gb2[tid] = gamma[tid]; gb2[tid + 256] = beta[tid];
    int li = tid & 63;
    #pragma unroll 4
    for (int it = 0; it < 64; ++it) {
        int hh = (tid >> 6) + it * 4;
        yt[li][hh] = (short)ygb[(size_t)(b * 256 + hh) * 2048 + l0 + li];
    }
    __syncthreads();
    const short* brow = &yt[16 * w + cc][0];
    bf16x8 bfr[8];
    #pragma unroll
    for (int ks = 0; ks < 8; ++ks) bfr[ks] = *(const bf16x8*)(brow + ks * 32 + gg * 8);
    f32x4 acc[32];
    #pragma unroll
    for (int tt = 0; tt < 32; ++tt) acc[tt] = (f32x4){0.f, 0.f, 0.f, 0.f};
    const int fr = tid >> 5, fch = tid & 31;
    bf16x8 pre[8];
    #pragma unroll
    for (int j = 0; j < 8; ++j)
        pre[j] = *(const bf16x8*)(Wb + (size_t)(fr + j * 8) * 256 + fch * 8);
    #pragma unroll
    for (int c = 0; c < 8; ++c) {
        #pragma unroll
        for (int j = 0; j < 8; ++j)
            *(bf16x8*)&Wl[fr + j * 8][fch * 8] = pre[j];
        __syncthreads();
        if (c < 7) {
            #pragma unroll
            for (int j = 0; j < 8; ++j)
                pre[j] = *(const bf16x8*)(Wb + (size_t)((c + 1) * 64 + fr + j * 8) * 256 + fch * 8);
        }
        #pragma unroll
        for (int ks = 0; ks < 8; ++ks) {
            #pragma unroll
            for (int tl = 0; tl < 4; ++tl) {
                bf16x8 afrag = *(const bf16x8*)&Wl[tl * 16 + cc][ks * 32 + gg * 8];
                acc[c * 4 + tl] = __builtin_amdgcn_mfma_f32_16x16x32_bf16(
                    afrag, bfr[ks], acc[c * 4 + tl], 0, 0, 0);
            }
        }
        __syncthreads();
    }
    // stage residual u tile (yt/Wl dead): uS[hh][l] = u[b][hh][l0+l], coalesced
    for (int i = tid; i < 256 * 64; i += 256) {
        int hh = i >> 6, l = i & 63;
        uS[hh][l] = u[(size_t)(b * 256 + hh) * 2048 + l0 + l];
    }
    __syncthreads();
    int llocal = 16 * w + cc;
    float s = 0.f, q2 = 0.f;
    #pragma unroll
    for (int tt = 0; tt < 16; ++tt) {
        #pragma unroll
        for (int r = 0; r < 4; ++r) {
            int P = tt * 16 + gg * 4 + r;
            float ya = acc[tt][r] + bo[P];
            float gb = acc[tt + 16][r] + bo[256 + P];
            float gv = ya / (1.0f + expf(-gb));
            float val = gv + uS[P][llocal];
            acc[tt][r] = val;
            s += val; q2 += val * val;
        }
    }
    s  += __shfl_xor(s, 16);  s  += __shfl_xor(s, 32);
    q2 += __shfl_xor(q2, 16); q2 += __shfl_xor(q2, 32);
    float mu = s * (1.0f / 256.0f);
    float var = q2 * (1.0f / 256.0f) - mu * mu;
    float rstd = rsqrtf(var + 1e-5f);
    float* ob = out + (size_t)((l0 + llocal) * 16 + b) * 256;
    #pragma unroll
    for (int tt = 0; tt < 16; ++tt) {
        int P0 = tt * 16 + gg * 4;
        float4 o4;
        o4.x = (acc[tt][0] - mu) * rstd * gb2[P0 + 0] + gb2[256 + P0 + 0];
        o4.y = (acc[tt][1] - mu) * rstd * gb2[P0 + 1] + gb2[256 + P0 + 1];
        o4.z = (acc[tt][2] - mu) * rstd * gb2[P0 + 2] + gb2[256 + P0 + 2];
        o4.w = (acc[tt][3] - mu) * rstd * gb2[P0 + 3] + gb2[256 + P0 + 3];
        *(float4*)(ob + P0) = o4;
    }
}

// ---------------- launch ----------------
extern "C" void kernel_launch(void* const* d_in, const int* in_sizes, int n_in,
                              void* d_out, int out_size, void* d_ws, size_t ws_size,
                              hipStream_t stream)
{
    (void)in_sizes; (void)n_in; (void)out_size; (void)ws_size;
    const float* x      = (const float*)d_in[0];
    const float* log_dt = (const float*)d_in[1];
    const float* wlr    = (const float*)d_in[2];
    const float* wim    = (const float*)d_in[3];
    const float* Pre    = (const float*)d_in[4];
    const float* Pim    = (const float*)d_in[5];
    const float* Bre    = (const float*)d_in[6];
    const float* Bim    = (const float*)d_in[7];
    const float* Cre    = (const float*)d_in[8];
    const float* Cim    = (const float*)d_in[9];
    const float* Dp     = (const float*)d_in[10];
    const float* Wout   = (const float*)d_in[11];
    const float* bout   = (const float*)d_in[12];
    const float* gamma  = (const float*)d_in[13];
    const float* beta   = (const float*)d_in[14];

    float* ws  = (float*)d_ws;
    float* u   = ws;                              // 32MB (B,H,L) f32
    unsigned short* ygb = (unsigned short*)(ws + 8388608);   // 16MB (B,H,L) bf16
    char*  ob  = (char*)d_out;
    float2* kF  = (float2*)(ob);                       // 4,198,400 B
    float2* kfo = (float2*)(ob + 4198400);             // 4,196,352 B
    unsigned short* Wb = (unsigned short*)(ob + 8394752);  // 262,144 B

    k0_convW<<<dim3(512), 256, 0, stream>>>(Wout, Wb);
    k1_kergen<<<dim3(256, 5), 256, 0, stream>>>(log_dt, wlr, wim, Pre, Pim, Bre, Bim, Cre, Cim, kF);
    k2_kernelfft<<<dim3(256), 1024, 0, stream>>>(kF, kfo);
    k3_transpose<<<dim3(128, 64), dim3(32, 8), 0, stream>>>(x, u);
    k4_conv<<<dim3(2048), 256, 0, stream>>>(u, kfo, Dp, ygb);
    k56_gemm_glu_ln<<<dim3(32, 16), 256, 0, stream>>>(ygb, Wb, bout, u, gamma, beta, (float*)d_out);
}

// Round 15
// 125.596 us; speedup vs baseline: 1.0965x; 1.0965x over previous
//
#include <hip/hip_runtime.h>

// S4 (SSSD) layer: L=2048, B=16, H=256, N2=32. Output f32.
// R15: k4 launch-bounds regression reverted (R14's (256,4) capped VGPR->64 and
// spilled: WRITE_SIZE 16->108MB). Added log-depth twiddle tree (was 15-deep
// dependent cmul chain) and half-zero/half-out fft16 specializations.
// Keeps R14's k2@1024 and k56 LDS-staged residual.

#define PI_F 3.14159265358979323846f
#define LP(i) ((i) + ((i) >> 4))    // LDS pad for k2's fft_fused

typedef __attribute__((ext_vector_type(8))) short bf16x8;
typedef __attribute__((ext_vector_type(4))) float f32x4;

__device__ __forceinline__ float2 cmulf(float2 a, float2 b) {
    return make_float2(a.x*b.x - a.y*b.y, a.x*b.y + a.y*b.x);
}
__device__ __forceinline__ unsigned short f2bf(float f) {
    unsigned int u = __float_as_uint(f);
    u += 0x7fffu + ((u >> 16) & 1u);
    return (unsigned short)(u >> 16);
}

// ------ 16-pt register FFT; HZ: odd post-bitrev inputs are zero (stage 0 =
// copies); HO: only outputs 0..7 needed (last stage computes "+" half only) --
template<int SGN, bool HZ, bool HO>
__device__ __forceinline__ void fft16(float2 v[16]) {
    float2 tsw;
#define SW(i,j) { tsw = v[i]; v[i] = v[j]; v[j] = tsw; }
    SW(1,8) SW(2,4) SW(3,12) SW(5,10) SW(7,14) SW(11,13)
#undef SW
    const float C8[8] = {1.f, 0.92387953251f, 0.70710678119f, 0.38268343236f,
                         0.f, -0.38268343236f, -0.70710678119f, -0.92387953251f};
    const float S8[8] = {0.f, 0.38268343236f, 0.70710678119f, 0.92387953251f,
                         1.f, 0.92387953251f, 0.70710678119f, 0.38268343236f};
    #pragma unroll
    for (int s = 0; s < 4; ++s) {
        const int Ns = 1 << s;
        #pragma unroll
        for (int j = 0; j < 8; ++j) {
            const int k  = j & (Ns - 1);
            const int i0 = ((j >> s) << (s + 1)) | k;
            const int i1 = i0 + Ns;
            if (HZ && s == 0) { v[i1] = v[i0]; continue; }   // b==0, w==1
            const int ti = k << (3 - s);
            const float cs = C8[ti];
            const float sn = (SGN < 0) ? -S8[ti] : S8[ti];
            float2 a = v[i0], b = v[i1];
            float2 t = make_float2(cs*b.x - sn*b.y, cs*b.y + sn*b.x);
            v[i0] = make_float2(a.x + t.x, a.y + t.y);
            if (!(HO && s == 3)) v[i1] = make_float2(a.x - t.x, a.y - t.y);
        }
    }
}

// ---- apply v[k] *= w^k, k=1..15, w = e^{i*ang}; log-depth power tree -------
__device__ __forceinline__ void tw_apply(float2 v[16], float ang) {
    float sn, cs;
    __sincosf(ang, &sn, &cs);
    float2 W1 = make_float2(cs, sn);
    float2 W2 = cmulf(W1, W1);
    float2 W3 = cmulf(W2, W1);
    float2 W4 = cmulf(W2, W2);
    float2 W5 = cmulf(W4, W1);
    float2 W6 = cmulf(W4, W2);
    float2 W7 = cmulf(W4, W3);
    float2 W8 = cmulf(W4, W4);
    v[1] = cmulf(v[1], W1);   v[2] = cmulf(v[2], W2);
    v[3] = cmulf(v[3], W3);   v[4] = cmulf(v[4], W4);
    v[5] = cmulf(v[5], W5);   v[6] = cmulf(v[6], W6);
    v[7] = cmulf(v[7], W7);   v[8] = cmulf(v[8], W8);
    v[9]  = cmulf(v[9],  cmulf(W8, W1));
    v[10] = cmulf(v[10], cmulf(W8, W2));
    v[11] = cmulf(v[11], cmulf(W8, W3));
    v[12] = cmulf(v[12], cmulf(W8, W4));
    v[13] = cmulf(v[13], cmulf(W8, W5));
    v[14] = cmulf(v[14], cmulf(W8, W6));
    v[15] = cmulf(v[15], cmulf(W8, W7));
}

// ------------- 4096-pt FFT: 3 phases of fft16, 2 LDS transposes -------------
// HZ: input upper half zero (fwd conv path). HO: only outputs 0..2047 needed.
template<int SGN, bool HZ, bool HO>
__device__ __forceinline__ void fft4096p(float2 v[16], float2* lds, int t) {
    fft16<SGN, HZ, false>(v);
    tw_apply(v, (float)SGN * (2.0f * PI_F / 4096.0f) * (float)t);
    __syncthreads();
    #pragma unroll
    for (int k = 0; k < 16; ++k) lds[t * 17 + k] = v[k];
    __syncthreads();
    const int k1 = t & 15, m2 = t >> 4;
    #pragma unroll
    for (int m1 = 0; m1 < 16; ++m1) v[m1] = lds[(m1 * 16 + m2) * 17 + k1];
    fft16<SGN, false, false>(v);
    tw_apply(v, (float)SGN * (2.0f * PI_F / 256.0f) * (float)m2);
    __syncthreads();
    #pragma unroll
    for (int j = 0; j < 16; ++j) lds[m2 * 273 + j * 17 + k1] = v[j];
    __syncthreads();
    #pragma unroll
    for (int m = 0; m < 16; ++m) v[m] = lds[m * 273 + (t >> 4) * 17 + k1];
    fft16<SGN, false, HO>(v);
}

// -------- in-LDS fused double-stage FFT (k2; nthr-parameterized) ------------
template<int SGN>
__device__ __forceinline__ void fft_fused(float2* A, int N, int logN,
                                          int tid, int nthr) {
    __syncthreads();
    for (int j = tid; j < N; j += nthr) {
        int r = (int)(__brev((unsigned)j) >> (32 - logN));
        if (r > j) { float2 t = A[LP(j)]; A[LP(j)] = A[LP(r)]; A[LP(r)] = t; }
    }
    __syncthreads();
    int s = 0;
    if (logN & 1) {
        for (int j = tid; j < (N >> 1); j += nthr) {
            int i0 = 2 * j;
            float2 a = A[LP(i0)], b = A[LP(i0 + 1)];
            A[LP(i0)]     = make_float2(a.x + b.x, a.y + b.y);
            A[LP(i0 + 1)] = make_float2(a.x - b.x, a.y - b.y);
        }
        __syncthreads();
        s = 1;
    }
    for (; s < logN; s += 2) {
        const int Ns = 1 << s;
        for (int g = tid; g < (N >> 2); g += nthr) {
            int k = g & (Ns - 1);
            int base = ((g >> s) << (s + 2)) | k;
            float2 a0 = A[LP(base)];
            float2 a1 = A[LP(base + Ns)];
            float2 a2 = A[LP(base + 2*Ns)];
            float2 a3 = A[LP(base + 3*Ns)];
            float ang1 = (float)SGN * PI_F * (float)k / (float)Ns;
            float sn1, cs1; __sincosf(ang1, &sn1, &cs1);
            float2 t = make_float2(cs1*a1.x - sn1*a1.y, cs1*a1.y + sn1*a1.x);
            float2 b0 = make_float2(a0.x + t.x, a0.y + t.y);
            float2 b1 = make_float2(a0.x - t.x, a0.y - t.y);
            t = make_float2(cs1*a3.x - sn1*a3.y, cs1*a3.y + sn1*a3.x);
            float2 b2 = make_float2(a2.x + t.x, a2.y + t.y);
            float2 b3 = make_float2(a2.x - t.x, a2.y - t.y);
            float ang2 = (float)SGN * PI_F * (float)k / (float)(2 * Ns);
            float sn2, cs2; __sincosf(ang2, &sn2, &cs2);
            t = make_float2(cs2*b2.x - sn2*b2.y, cs2*b2.y + sn2*b2.x);
            A[LP(base)]        = make_float2(b0.x + t.x, b0.y + t.y);
            A[LP(base + 2*Ns)] = make_float2(b0.x - t.x, b0.y - t.y);
            float c2p, s2p;
            if (SGN < 0) { c2p = sn2; s2p = -cs2; } else { c2p = -sn2; s2p = cs2; }
            t = make_float2(c2p*b3.x - s2p*b3.y, c2p*b3.y + s2p*b3.x);
            A[LP(base + Ns)]   = make_float2(b1.x + t.x, b1.y + t.y);
            A[LP(base + 3*Ns)] = make_float2(b1.x - t.x, b1.y - t.y);
        }
        __syncthreads();
    }
}

// ---------------- K0: convert W [512][256] f32 -> bf16 (row-major) ----------
__global__ void k0_convW(const float* __restrict__ W, unsigned short* __restrict__ Wb)
{
    int i = blockIdx.x * 256 + threadIdx.x;
    if (i < 512 * 256) Wb[i] = f2bf(W[i]);
}

// ---------------- K1: NPLR kernel generation (f32, rcp + packed LDS) --------
__global__ __launch_bounds__(256) void k1_kergen(const float* __restrict__ log_dt,
                          const float* __restrict__ wlr, const float* __restrict__ wim,
                          const float* __restrict__ Pre, const float* __restrict__ Pim,
                          const float* __restrict__ Bre, const float* __restrict__ Bim,
                          const float* __restrict__ Cre, const float* __restrict__ Cim,
                          float2* __restrict__ kf_out)
{
    __shared__ float4 T0[32], T1[32], T2[32], T3[32];
    int h = blockIdx.x;
    int tid = threadIdx.x;
    float dt = expf(log_dt[h]);
    if (tid < 32) {
        int i = h * 32 + tid;
        float wre = -expf(wlr[i]) * dt;
        float wi  = wim[i] * dt;
        float2 B  = make_float2(Bre[i], Bim[i]);
        float2 P  = make_float2(Pre[i], Pim[i]);
        float2 C0 = make_float2(Cre[i], Cim[i]);
        float2 C1 = make_float2(Cre[8192 + i], Cim[8192 + i]);
        float2 Pc = make_float2(P.x, -P.y);
        float2 v00 = cmulf(B, C0), v01 = cmulf(B, C1), v02 = cmulf(B, Pc);
        float2 v10 = cmulf(P, C0), v11 = cmulf(P, C1), v12 = cmulf(P, Pc);
        T0[tid] = make_float4(wre, wi, v00.x, v00.y);
        T1[tid] = make_float4(v01.x, v01.y, v02.x, v02.y);
        T2[tid] = make_float4(v10.x, v10.y, v11.x, v11.y);
        T3[tid] = make_float4(v12.x, v12.y, 0.f, 0.f);
    }
    __syncthreads();
    int f = blockIdx.y * 256 + tid;
    if (f > 1024) return;
    float ang = -(2.0f * PI_F / 2048.0f) * (float)f;
    float sn, cs;
    sincosf(ang, &sn, &cs);
    float2 onep = make_float2(1.0f + cs, sn);
    float invo = __builtin_amdgcn_rcpf(onep.x * onep.x + onep.y * onep.y);
    float2 oinv = make_float2(onep.x * invo, -onep.y * invo);
    float2 z = cmulf(make_float2(2.0f * (1.0f - cs), -2.0f * sn), oinv);
    float2 r00 = {0,0}, r01 = {0,0}, r02 = {0,0};
    float2 r10 = {0,0}, r11 = {0,0}, r12 = {0,0};
    #pragma unroll 4
    for (int n = 0; n < 32; ++n) {
        float4 a  = T0[n];
        float4 bq = T1[n];
        float4 cq = T2[n];
        float4 dq = T3[n];
        float zx  = z.x - a.x;
        float d1y = z.y - a.y;
        float d2y = z.y + a.y;
        float inv1 = __builtin_amdgcn_rcpf(zx * zx + d1y * d1y);
        float inv2 = __builtin_amdgcn_rcpf(zx * zx + d2y * d2y);
        float sx = zx * (inv1 + inv2);
        float dx = zx * (inv1 - inv2);
        float sy = -(d1y * inv1 + d2y * inv2);
        float dy = d1y * inv1 - d2y * inv2;
        r00.x += a.z*sx + a.w*dy;  r00.y += a.z*sy + a.w*dx;
        r01.x += bq.x*sx + bq.y*dy; r01.y += bq.x*sy + bq.y*dx;
        r02.x += bq.z*sx + bq.w*dy; r02.y += bq.z*sy + bq.w*dx;
        r10.x += cq.x*sx + cq.y*dy; r10.y += cq.x*sy + cq.y*dx;
        r11.x += cq.z*sx + cq.w*dy; r11.y += cq.z*sy + cq.w*dx;
        r12.x += dq.x*sx + dq.y*dy; r12.y += dq.x*sy + dq.y*dx;
    }
    r00.x *= dt; r00.y *= dt; r01.x *= dt; r01.y *= dt; r02.x *= dt; r02.y *= dt;
    r10.x *= dt; r10.y *= dt; r11.x *= dt; r11.y *= dt; r12.x *= dt; r12.y *= dt;
    float2 den = make_float2(1.0f + r12.x, r12.y);
    float invd = __builtin_amdgcn_rcpf(den.x * den.x + den.y * den.y);
    float2 idn = make_float2(den.x * invd, -den.y * invd);
    float2 fac = make_float2(2.0f * oinv.x, 2.0f * oinv.y);
    float2 t0 = cmulf(cmulf(r02, r10), idn);
    float2 k0 = cmulf(make_float2(r00.x - t0.x, r00.y - t0.y), fac);
    float2 t1 = cmulf(cmulf(r02, r11), idn);
    float2 k1 = cmulf(make_float2(r01.x - t1.x, r01.y - t1.y), fac);
    kf_out[(size_t)h * 1025 + f]         = k0;
    kf_out[(size_t)(256 + h) * 1025 + f] = k1;
}

// ---------------- K2: packed irfft(ch0,ch1) -> kk -> fft4096 -> kf ----------
__global__ __launch_bounds__(1024) void k2_kernelfft(const float2* __restrict__ kfin,
                                                     float2* __restrict__ kfout)
{
    __shared__ float2 A2[2176];
    __shared__ float2 A4[4352];
    int h = blockIdx.x, tid = threadIdx.x;
    const int NT = 1024;
    const float2* s0 = kfin + (size_t)h * 1025;
    const float2* s1 = kfin + (size_t)(256 + h) * 1025;
    for (int j = tid; j < 2048; j += NT) {
        float2 q0, q1;
        if (j == 0)          { q0 = s0[0];    q0.y = 0.0f; q1 = s1[0];    q1.y = 0.0f; }
        else if (j < 1024)   { q0 = s0[j];                 q1 = s1[j]; }
        else if (j == 1024)  { q0 = s0[1024]; q0.y = 0.0f; q1 = s1[1024]; q1.y = 0.0f; }
        else { float2 t0 = s0[2048 - j], t1 = s1[2048 - j];
               q0 = make_float2(t0.x, -t0.y); q1 = make_float2(t1.x, -t1.y); }
        A2[LP(j)] = make_float2(q0.x - q1.y, q0.y + q1.x);   // E0 + i*E1
    }
    fft_fused<+1>(A2, 2048, 11, tid, NT);
    const float scl = 1.0f / 2048.0f;
    for (int j = tid; j < 2048; j += NT) {
        float2 v = A2[LP(j)];
        A4[LP(j)]        = make_float2(v.x * scl, 0.0f);
        A4[LP(4095 - j)] = make_float2(v.y * scl, 0.0f);
    }
    fft_fused<-1>(A4, 4096, 12, tid, NT);
    for (int F = tid; F <= 2048; F += NT)
        kfout[(size_t)h * 2049 + F] = A4[LP(F)];
}

// ---------------- K3: transpose x (2048 x 4096) -> u (4096 x 2048) ----------
__global__ void k3_transpose(const float* __restrict__ x, float* __restrict__ u)
{
    __shared__ float tile[32][33];
    int p0 = blockIdx.x * 32;
    int l0 = blockIdx.y * 32;
    int tx = threadIdx.x, ty = threadIdx.y;
    for (int i = ty; i < 32; i += 8)
        tile[i][tx] = x[(size_t)(l0 + i) * 4096 + p0 + tx];
    __syncthreads();
    for (int i = ty; i < 32; i += 8)
        u[(size_t)(p0 + i) * 2048 + l0 + tx] = tile[tx][i];
}

// ---------------- K4: pair-packed conv via register radix-16 FFT ------------
__global__ __launch_bounds__(256) void k4_conv(const float* __restrict__ u,
        const float2* __restrict__ kf, const float* __restrict__ Dp,
        unsigned short* __restrict__ ygb)
{
    __shared__ float2 lds[4366];
    int h  = blockIdx.x & 255;
    int bp = blockIdx.x >> 8;
    int t  = threadIdx.x;
    const float* u0 = u + (size_t)((2*bp)   * 256 + h) * 2048;
    const float* u1 = u + (size_t)((2*bp+1) * 256 + h) * 2048;
    float2 v[16], us[8];
    #pragma unroll
    for (int n1 = 0; n1 < 8; ++n1) {
        int j = n1 * 256 + t;
        us[n1] = make_float2(u0[j], u1[j]);
        v[n1] = us[n1];
        v[n1 + 8] = make_float2(0.f, 0.f);
    }
    fft4096p<-1, true, false>(v, lds, t);
    const float2* kfh = kf + (size_t)h * 2049;
    #pragma unroll
    for (int j2 = 0; j2 < 16; ++j2) {
        int f = t + 256 * j2;
        float2 K;
        if (f <= 2048) K = kfh[f];
        else { float2 q = kfh[4096 - f]; K = make_float2(q.x, -q.y); }
        v[j2] = cmulf(v[j2], K);
    }
    fft4096p<+1, false, true>(v, lds, t);
    float d = Dp[h];
    unsigned short* o0 = ygb + (size_t)((2*bp)   * 256 + h) * 2048;
    unsigned short* o1 = ygb + (size_t)((2*bp+1) * 256 + h) * 2048;
    const float iscl = 1.0f / 4096.0f;
    #pragma unroll
    for (int j2 = 0; j2 < 8; ++j2) {
        int l = t + 256 * j2;
        float y0 = v[j2].x * iscl + d * us[j2].x;
        float y1 = v[j2].y * iscl + d * us[j2].y;
        o0[l] = f2bf(0.5f * y0 * (1.0f + erff(y0 * 0.70710678118654752f)));
        o1[l] = f2bf(0.5f * y1 * (1.0f + erff(y1 * 0.70710678118654752f)));
    }
}

// ---------------- K56: MFMA GEMM + GLU + residual + LayerNorm + store -------
__global__ __launch_bounds__(256, 2) void k56_gemm_glu_ln(const unsigned short* __restrict__ ygb,
        const unsigned short* __restrict__ Wb, const float* __restrict__ bout,
        const float* __restrict__ u, const float* __restrict__ gamma,
        const float* __restrict__ beta, float* __restrict__ out)
{
    __shared__ __align__(16) char smem[67584];
    short (*yt)[264] = (short(*)[264])smem;
    short (*Wl)[264] = (short(*)[264])(smem + 33792);
    float (*uS)[65]  = (float(*)[65])smem;
    __shared__ float bo[512];
    __shared__ float gb2[512];
    int b  = blockIdx.y;
    int l0 = blockIdx.x * 64;
    int tid = threadIdx.x;
    int lane = tid & 63, w = tid >> 6;
    int cc = lane & 15, gg = lane >> 4;
    bo[tid] = bout[tid]; bo[tid + 256] = bout[tid + 256];
    gb2[tid] = gamma[tid]; gb2[tid + 256] = beta[tid];
    int li = tid & 63;
    #pragma unroll 4
    for (int it = 0; it < 64; ++it) {
        int hh = (tid >> 6) + it * 4;
        yt[li][hh] = (short)ygb[(size_t)(b * 256 + hh) * 2048 + l0 + li];
    }
    __syncthreads();
    const short* brow = &yt[16 * w + cc][0];
    bf16x8 bfr[8];
    #pragma unroll
    for (int ks = 0; ks < 8; ++ks) bfr[ks] = *(const bf16x8*)(brow + ks * 32 + gg * 8);
    f32x4 acc[32];
    #pragma unroll
    for (int tt = 0; tt < 32; ++tt) acc[tt] = (f32x4){0.f, 0.f, 0.f, 0.f};
    const int fr = tid >> 5, fch = tid & 31;
    bf16x8 pre[8];
    #pragma unroll
    for (int j = 0; j < 8; ++j)
        pre[j] = *(const bf16x8*)(Wb + (size_t)(fr + j * 8) * 256 + fch * 8);
    #pragma unroll
    for (int c = 0; c < 8; ++c) {
        #pragma unroll
        for (int j = 0; j < 8; ++j)
            *(bf16x8*)&Wl[fr + j * 8][fch * 8] = pre[j];
        __syncthreads();
        if (c < 7) {
            #pragma unroll
            for (int j = 0; j < 8; ++j)
                pre[j] = *(const bf16x8*)(Wb + (size_t)((c + 1) * 64 + fr + j * 8) * 256 + fch * 8);
        }
        #pragma unroll
        for (int ks = 0; ks < 8; ++ks) {
            #pragma unroll
            for (int tl = 0; tl < 4; ++tl) {
                bf16x8 afrag = *(const bf16x8*)&Wl[tl * 16 + cc][ks * 32 + gg * 8];
                acc[c * 4 + tl] = __builtin_amdgcn_mfma_f32_16x16x32_bf16(
                    afrag, bfr[ks], acc[c * 4 + tl], 0, 0, 0);
            }
        }
        __syncthreads();
    }
    for (int i = tid; i < 256 * 64; i += 256) {
        int hh = i >> 6, l = i & 63;
        uS[hh][l] = u[(size_t)(b * 256 + hh) * 2048 + l0 + l];
    }
    __syncthreads();
    int llocal = 16 * w + cc;
    float s = 0.f, q2 = 0.f;
    #pragma unroll
    for (int tt = 0; tt < 16; ++tt) {
        #pragma unroll
        for (int r = 0; r < 4; ++r) {
            int P = tt * 16 + gg * 4 + r;
            float ya = acc[tt][r] + bo[P];
            float gb = acc[tt + 16][r] + bo[256 + P];
            float gv = ya / (1.0f + expf(-gb));
            float val = gv + uS[P][llocal];
            acc[tt][r] = val;
            s += val; q2 += val * val;
        }
    }
    s  += __shfl_xor(s, 16);  s  += __shfl_xor(s, 32);
    q2 += __shfl_xor(q2, 16); q2 += __shfl_xor(q2, 32);
    float mu = s * (1.0f / 256.0f);
    float var = q2 * (1.0f / 256.0f) - mu * mu;
    float rstd = rsqrtf(var + 1e-5f);
    float* ob = out + (size_t)((l0 + llocal) * 16 + b) * 256;
    #pragma unroll
    for (int tt = 0; tt < 16; ++tt) {
        int P0 = tt * 16 + gg * 4;
        float4 o4;
        o4.x = (acc[tt][0] - mu) * rstd * gb2[P0 + 0] + gb2[256 + P0 + 0];
        o4.y = (acc[tt][1] - mu) * rstd * gb2[P0 + 1] + gb2[256 + P0 + 1];
        o4.z = (acc[tt][2] - mu) * rstd * gb2[P0 + 2] + gb2[256 + P0 + 2];
        o4.w = (acc[tt][3] - mu) * rstd * gb2[P0 + 3] + gb2[256 + P0 + 3];
        *(float4*)(ob + P0) = o4;
    }
}

// ---------------- launch ----------------
extern "C" void kernel_launch(void* const* d_in, const int* in_sizes, int n_in,
                              void* d_out, int out_size, void* d_ws, size_t ws_size,
                              hipStream_t stream)
{
    (void)in_sizes; (void)n_in; (void)out_size; (void)ws_size;
    const float* x      = (const float*)d_in[0];
    const float* log_dt = (const float*)d_in[1];
    const float* wlr    = (const float*)d_in[2];
    const float* wim    = (const float*)d_in[3];
    const float* Pre    = (const float*)d_in[4];
    const float* Pim    = (const float*)d_in[5];
    const float* Bre    = (const float*)d_in[6];
    const float* Bim    = (const float*)d_in[7];
    const float* Cre    = (const float*)d_in[8];
    const float* Cim    = (const float*)d_in[9];
    const float* Dp     = (const float*)d_in[10];
    const float* Wout   = (const float*)d_in[11];
    const float* bout   = (const float*)d_in[12];
    const float* gamma  = (const float*)d_in[13];
    const float* beta   = (const float*)d_in[14];

    float* ws  = (float*)d_ws;
    float* u   = ws;                              // 32MB (B,H,L) f32
    unsigned short* ygb = (unsigned short*)(ws + 8388608);   // 16MB (B,H,L) bf16
    char*  ob  = (char*)d_out;
    float2* kF  = (float2*)(ob);                       // 4,198,400 B
    float2* kfo = (float2*)(ob + 4198400);             // 4,196,352 B
    unsigned short* Wb = (unsigned short*)(ob + 8394752);  // 262,144 B

    k0_convW<<<dim3(512), 256, 0, stream>>>(Wout, Wb);
    k1_kergen<<<dim3(256, 5), 256, 0, stream>>>(log_dt, wlr, wim, Pre, Pim, Bre, Bim, Cre, Cim, kF);
    k2_kernelfft<<<dim3(256), 1024, 0, stream>>>(kF, kfo);
    k3_transpose<<<dim3(128, 64), dim3(32, 8), 0, stream>>>(x, u);
    k4_conv<<<dim3(2048), 256, 0, stream>>>(u, kfo, Dp, ygb);
    k56_gemm_glu_ln<<<dim3(32, 16), 256, 0, stream>>>(ygb, Wb, bout, u, gamma, beta, (float*)d_out);
}

// Round 16
// 119.860 us; speedup vs baseline: 1.1490x; 1.0479x over previous
//
#include <hip/hip_runtime.h>

// S4 (SSSD) layer: L=2048, B=16, H=256, N2=32. Output f32.
// R16: u intermediate stored as bf16 (was f32) - halves k3 write, k4 read,
// k56 residual read (-48MB of ~190MB pipeline traffic). Precision budget:
// 2^-9 relative on conv input/residual ~ +0.01-0.02 absmax vs 0.105 threshold.
// k3 rebuilt: 64x64 tile, coalesced f32 loads, ushort4 bf16 writes.
// Rest identical to R15 (k4 twiddle-tree reg-FFT, k56 MFMA+LN fused).

#define PI_F 3.14159265358979323846f
#define LP(i) ((i) + ((i) >> 4))    // LDS pad for k2's fft_fused

typedef __attribute__((ext_vector_type(8))) short bf16x8;
typedef __attribute__((ext_vector_type(4))) float f32x4;

__device__ __forceinline__ float2 cmulf(float2 a, float2 b) {
    return make_float2(a.x*b.x - a.y*b.y, a.x*b.y + a.y*b.x);
}
__device__ __forceinline__ unsigned short f2bf(float f) {
    unsigned int u = __float_as_uint(f);
    u += 0x7fffu + ((u >> 16) & 1u);
    return (unsigned short)(u >> 16);
}
__device__ __forceinline__ float bf2f(unsigned short us) {
    return __uint_as_float((unsigned int)us << 16);
}

// ------ 16-pt register FFT; HZ: odd post-bitrev inputs are zero (stage 0 =
// copies); HO: only outputs 0..7 needed (last stage computes "+" half only) --
template<int SGN, bool HZ, bool HO>
__device__ __forceinline__ void fft16(float2 v[16]) {
    float2 tsw;
#define SW(i,j) { tsw = v[i]; v[i] = v[j]; v[j] = tsw; }
    SW(1,8) SW(2,4) SW(3,12) SW(5,10) SW(7,14) SW(11,13)
#undef SW
    const float C8[8] = {1.f, 0.92387953251f, 0.70710678119f, 0.38268343236f,
                         0.f, -0.38268343236f, -0.70710678119f, -0.92387953251f};
    const float S8[8] = {0.f, 0.38268343236f, 0.70710678119f, 0.92387953251f,
                         1.f, 0.92387953251f, 0.70710678119f, 0.38268343236f};
    #pragma unroll
    for (int s = 0; s < 4; ++s) {
        const int Ns = 1 << s;
        #pragma unroll
        for (int j = 0; j < 8; ++j) {
            const int k  = j & (Ns - 1);
            const int i0 = ((j >> s) << (s + 1)) | k;
            const int i1 = i0 + Ns;
            if (HZ && s == 0) { v[i1] = v[i0]; continue; }   // b==0, w==1
            const int ti = k << (3 - s);
            const float cs = C8[ti];
            const float sn = (SGN < 0) ? -S8[ti] : S8[ti];
            float2 a = v[i0], b = v[i1];
            float2 t = make_float2(cs*b.x - sn*b.y, cs*b.y + sn*b.x);
            v[i0] = make_float2(a.x + t.x, a.y + t.y);
            if (!(HO && s == 3)) v[i1] = make_float2(a.x - t.x, a.y - t.y);
        }
    }
}

// ---- apply v[k] *= w^k, k=1..15, w = e^{i*ang}; log-depth power tree -------
__device__ __forceinline__ void tw_apply(float2 v[16], float ang) {
    float sn, cs;
    __sincosf(ang, &sn, &cs);
    float2 W1 = make_float2(cs, sn);
    float2 W2 = cmulf(W1, W1);
    float2 W3 = cmulf(W2, W1);
    float2 W4 = cmulf(W2, W2);
    float2 W5 = cmulf(W4, W1);
    float2 W6 = cmulf(W4, W2);
    float2 W7 = cmulf(W4, W3);
    float2 W8 = cmulf(W4, W4);
    v[1] = cmulf(v[1], W1);   v[2] = cmulf(v[2], W2);
    v[3] = cmulf(v[3], W3);   v[4] = cmulf(v[4], W4);
    v[5] = cmulf(v[5], W5);   v[6] = cmulf(v[6], W6);
    v[7] = cmulf(v[7], W7);   v[8] = cmulf(v[8], W8);
    v[9]  = cmulf(v[9],  cmulf(W8, W1));
    v[10] = cmulf(v[10], cmulf(W8, W2));
    v[11] = cmulf(v[11], cmulf(W8, W3));
    v[12] = cmulf(v[12], cmulf(W8, W4));
    v[13] = cmulf(v[13], cmulf(W8, W5));
    v[14] = cmulf(v[14], cmulf(W8, W6));
    v[15] = cmulf(v[15], cmulf(W8, W7));
}

// ------------- 4096-pt FFT: 3 phases of fft16, 2 LDS transposes -------------
template<int SGN, bool HZ, bool HO>
__device__ __forceinline__ void fft4096p(float2 v[16], float2* lds, int t) {
    fft16<SGN, HZ, false>(v);
    tw_apply(v, (float)SGN * (2.0f * PI_F / 4096.0f) * (float)t);
    __syncthreads();
    #pragma unroll
    for (int k = 0; k < 16; ++k) lds[t * 17 + k] = v[k];
    __syncthreads();
    const int k1 = t & 15, m2 = t >> 4;
    #pragma unroll
    for (int m1 = 0; m1 < 16; ++m1) v[m1] = lds[(m1 * 16 + m2) * 17 + k1];
    fft16<SGN, false, false>(v);
    tw_apply(v, (float)SGN * (2.0f * PI_F / 256.0f) * (float)m2);
    __syncthreads();
    #pragma unroll
    for (int j = 0; j < 16; ++j) lds[m2 * 273 + j * 17 + k1] = v[j];
    __syncthreads();
    #pragma unroll
    for (int m = 0; m < 16; ++m) v[m] = lds[m * 273 + (t >> 4) * 17 + k1];
    fft16<SGN, false, HO>(v);
}

// -------- in-LDS fused double-stage FFT (k2; nthr-parameterized) ------------
template<int SGN>
__device__ __forceinline__ void fft_fused(float2* A, int N, int logN,
                                          int tid, int nthr) {
    __syncthreads();
    for (int j = tid; j < N; j += nthr) {
        int r = (int)(__brev((unsigned)j) >> (32 - logN));
        if (r > j) { float2 t = A[LP(j)]; A[LP(j)] = A[LP(r)]; A[LP(r)] = t; }
    }
    __syncthreads();
    int s = 0;
    if (logN & 1) {
        for (int j = tid; j < (N >> 1); j += nthr) {
            int i0 = 2 * j;
            float2 a = A[LP(i0)], b = A[LP(i0 + 1)];
            A[LP(i0)]     = make_float2(a.x + b.x, a.y + b.y);
            A[LP(i0 + 1)] = make_float2(a.x - b.x, a.y - b.y);
        }
        __syncthreads();
        s = 1;
    }
    for (; s < logN; s += 2) {
        const int Ns = 1 << s;
        for (int g = tid; g < (N >> 2); g += nthr) {
            int k = g & (Ns - 1);
            int base = ((g >> s) << (s + 2)) | k;
            float2 a0 = A[LP(base)];
            float2 a1 = A[LP(base + Ns)];
            float2 a2 = A[LP(base + 2*Ns)];
            float2 a3 = A[LP(base + 3*Ns)];
            float ang1 = (float)SGN * PI_F * (float)k / (float)Ns;
            float sn1, cs1; __sincosf(ang1, &sn1, &cs1);
            float2 t = make_float2(cs1*a1.x - sn1*a1.y, cs1*a1.y + sn1*a1.x);
            float2 b0 = make_float2(a0.x + t.x, a0.y + t.y);
            float2 b1 = make_float2(a0.x - t.x, a0.y - t.y);
            t = make_float2(cs1*a3.x - sn1*a3.y, cs1*a3.y + sn1*a3.x);
            float2 b2 = make_float2(a2.x + t.x, a2.y + t.y);
            float2 b3 = make_float2(a2.x - t.x, a2.y - t.y);
            float ang2 = (float)SGN * PI_F * (float)k / (float)(2 * Ns);
            float sn2, cs2; __sincosf(ang2, &sn2, &cs2);
            t = make_float2(cs2*b2.x - sn2*b2.y, cs2*b2.y + sn2*b2.x);
            A[LP(base)]        = make_float2(b0.x + t.x, b0.y + t.y);
            A[LP(base + 2*Ns)] = make_float2(b0.x - t.x, b0.y - t.y);
            float c2p, s2p;
            if (SGN < 0) { c2p = sn2; s2p = -cs2; } else { c2p = -sn2; s2p = cs2; }
            t = make_float2(c2p*b3.x - s2p*b3.y, c2p*b3.y + s2p*b3.x);
            A[LP(base + Ns)]   = make_float2(b1.x + t.x, b1.y + t.y);
            A[LP(base + 3*Ns)] = make_float2(b1.x - t.x, b1.y - t.y);
        }
        __syncthreads();
    }
}

// ---------------- K0: convert W [512][256] f32 -> bf16 (row-major) ----------
__global__ void k0_convW(const float* __restrict__ W, unsigned short* __restrict__ Wb)
{
    int i = blockIdx.x * 256 + threadIdx.x;
    if (i < 512 * 256) Wb[i] = f2bf(W[i]);
}

// ---------------- K1: NPLR kernel generation (f32, rcp + packed LDS) --------
__global__ __launch_bounds__(256) void k1_kergen(const float* __restrict__ log_dt,
                          const float* __restrict__ wlr, const float* __restrict__ wim,
                          const float* __restrict__ Pre, const float* __restrict__ Pim,
                          const float* __restrict__ Bre, const float* __restrict__ Bim,
                          const float* __restrict__ Cre, const float* __restrict__ Cim,
                          float2* __restrict__ kf_out)
{
    __shared__ float4 T0[32], T1[32], T2[32], T3[32];
    int h = blockIdx.x;
    int tid = threadIdx.x;
    float dt = expf(log_dt[h]);
    if (tid < 32) {
        int i = h * 32 + tid;
        float wre = -expf(wlr[i]) * dt;
        float wi  = wim[i] * dt;
        float2 B  = make_float2(Bre[i], Bim[i]);
        float2 P  = make_float2(Pre[i], Pim[i]);
        float2 C0 = make_float2(Cre[i], Cim[i]);
        float2 C1 = make_float2(Cre[8192 + i], Cim[8192 + i]);
        float2 Pc = make_float2(P.x, -P.y);
        float2 v00 = cmulf(B, C0), v01 = cmulf(B, C1), v02 = cmulf(B, Pc);
        float2 v10 = cmulf(P, C0), v11 = cmulf(P, C1), v12 = cmulf(P, Pc);
        T0[tid] = make_float4(wre, wi, v00.x, v00.y);
        T1[tid] = make_float4(v01.x, v01.y, v02.x, v02.y);
        T2[tid] = make_float4(v10.x, v10.y, v11.x, v11.y);
        T3[tid] = make_float4(v12.x, v12.y, 0.f, 0.f);
    }
    __syncthreads();
    int f = blockIdx.y * 256 + tid;
    if (f > 1024) return;
    float ang = -(2.0f * PI_F / 2048.0f) * (float)f;
    float sn, cs;
    sincosf(ang, &sn, &cs);
    float2 onep = make_float2(1.0f + cs, sn);
    float invo = __builtin_amdgcn_rcpf(onep.x * onep.x + onep.y * onep.y);
    float2 oinv = make_float2(onep.x * invo, -onep.y * invo);
    float2 z = cmulf(make_float2(2.0f * (1.0f - cs), -2.0f * sn), oinv);
    float2 r00 = {0,0}, r01 = {0,0}, r02 = {0,0};
    float2 r10 = {0,0}, r11 = {0,0}, r12 = {0,0};
    #pragma unroll 4
    for (int n = 0; n < 32; ++n) {
        float4 a  = T0[n];
        float4 bq = T1[n];
        float4 cq = T2[n];
        float4 dq = T3[n];
        float zx  = z.x - a.x;
        float d1y = z.y - a.y;
        float d2y = z.y + a.y;
        float inv1 = __builtin_amdgcn_rcpf(zx * zx + d1y * d1y);
        float inv2 = __builtin_amdgcn_rcpf(zx * zx + d2y * d2y);
        float sx = zx * (inv1 + inv2);
        float dx = zx * (inv1 - inv2);
        float sy = -(d1y * inv1 + d2y * inv2);
        float dy = d1y * inv1 - d2y * inv2;
        r00.x += a.z*sx + a.w*dy;  r00.y += a.z*sy + a.w*dx;
        r01.x += bq.x*sx + bq.y*dy; r01.y += bq.x*sy + bq.y*dx;
        r02.x += bq.z*sx + bq.w*dy; r02.y += bq.z*sy + bq.w*dx;
        r10.x += cq.x*sx + cq.y*dy; r10.y += cq.x*sy + cq.y*dx;
        r11.x += cq.z*sx + cq.w*dy; r11.y += cq.z*sy + cq.w*dx;
        r12.x += dq.x*sx + dq.y*dy; r12.y += dq.x*sy + dq.y*dx;
    }
    r00.x *= dt; r00.y *= dt; r01.x *= dt; r01.y *= dt; r02.x *= dt; r02.y *= dt;
    r10.x *= dt; r10.y *= dt; r11.x *= dt; r11.y *= dt; r12.x *= dt; r12.y *= dt;
    float2 den = make_float2(1.0f + r12.x, r12.y);
    float invd = __builtin_amdgcn_rcpf(den.x * den.x + den.y * den.y);
    float2 idn = make_float2(den.x * invd, -den.y * invd);
    float2 fac = make_float2(2.0f * oinv.x, 2.0f * oinv.y);
    float2 t0 = cmulf(cmulf(r02, r10), idn);
    float2 k0 = cmulf(make_float2(r00.x - t0.x, r00.y - t0.y), fac);
    float2 t1 = cmulf(cmulf(r02, r11), idn);
    float2 k1 = cmulf(make_float2(r01.x - t1.x, r01.y - t1.y), fac);
    kf_out[(size_t)h * 1025 + f]         = k0;
    kf_out[(size_t)(256 + h) * 1025 + f] = k1;
}

// ---------------- K2: packed irfft(ch0,ch1) -> kk -> fft4096 -> kf ----------
__global__ __launch_bounds__(1024) void k2_kernelfft(const float2* __restrict__ kfin,
                                                     float2* __restrict__ kfout)
{
    __shared__ float2 A2[2176];
    __shared__ float2 A4[4352];
    int h = blockIdx.x, tid = threadIdx.x;
    const int NT = 1024;
    const float2* s0 = kfin + (size_t)h * 1025;
    const float2* s1 = kfin + (size_t)(256 + h) * 1025;
    for (int j = tid; j < 2048; j += NT) {
        float2 q0, q1;
        if (j == 0)          { q0 = s0[0];    q0.y = 0.0f; q1 = s1[0];    q1.y = 0.0f; }
        else if (j < 1024)   { q0 = s0[j];                 q1 = s1[j]; }
        else if (j == 1024)  { q0 = s0[1024]; q0.y = 0.0f; q1 = s1[1024]; q1.y = 0.0f; }
        else { float2 t0 = s0[2048 - j], t1 = s1[2048 - j];
               q0 = make_float2(t0.x, -t0.y); q1 = make_float2(t1.x, -t1.y); }
        A2[LP(j)] = make_float2(q0.x - q1.y, q0.y + q1.x);   // E0 + i*E1
    }
    fft_fused<+1>(A2, 2048, 11, tid, NT);
    const float scl = 1.0f / 2048.0f;
    for (int j = tid; j < 2048; j += NT) {
        float2 v = A2[LP(j)];
        A4[LP(j)]        = make_float2(v.x * scl, 0.0f);
        A4[LP(4095 - j)] = make_float2(v.y * scl, 0.0f);
    }
    fft_fused<-1>(A4, 4096, 12, tid, NT);
    for (int F = tid; F <= 2048; F += NT)
        kfout[(size_t)h * 2049 + F] = A4[LP(F)];
}

// ------- K3: transpose x (2048 x 4096) -> u_bf16 (4096 x 2048) --------------
// 64x64 tile; coalesced f32 loads, ushort4 bf16 writes.
__global__ __launch_bounds__(256) void k3_transpose(const float* __restrict__ x,
                                                    unsigned short* __restrict__ ub)
{
    __shared__ float tile[64][65];
    int p0 = blockIdx.x * 64;
    int l0 = blockIdx.y * 64;
    int t  = threadIdx.x;
    int q = t & 15, r = t >> 4;
    #pragma unroll
    for (int k = 0; k < 4; ++k) {
        int row = r + k * 16;   // l-row
        float4 v = *(const float4*)&x[(size_t)(l0 + row) * 4096 + p0 + q * 4];
        tile[row][q*4+0] = v.x; tile[row][q*4+1] = v.y;
        tile[row][q*4+2] = v.z; tile[row][q*4+3] = v.w;
    }
    __syncthreads();
    #pragma unroll
    for (int g = 0; g < 4; ++g) {
        int ch = t + 256 * g;        // 1024 ushort4 chunks
        int p = ch >> 4, c = ch & 15;
        ushort4 pk;
        pk.x = f2bf(tile[c*4+0][p]);
        pk.y = f2bf(tile[c*4+1][p]);
        pk.z = f2bf(tile[c*4+2][p]);
        pk.w = f2bf(tile[c*4+3][p]);
        *(ushort4*)&ub[(size_t)(p0 + p) * 2048 + l0 + c * 4] = pk;
    }
}

// ---------------- K4: pair-packed conv via register radix-16 FFT ------------
__global__ __launch_bounds__(256) void k4_conv(const unsigned short* __restrict__ ub,
        const float2* __restrict__ kf, const float* __restrict__ Dp,
        unsigned short* __restrict__ ygb)
{
    __shared__ float2 lds[4366];
    int h  = blockIdx.x & 255;
    int bp = blockIdx.x >> 8;
    int t  = threadIdx.x;
    const unsigned short* u0 = ub + (size_t)((2*bp)   * 256 + h) * 2048;
    const unsigned short* u1 = ub + (size_t)((2*bp+1) * 256 + h) * 2048;
    float2 v[16], us[8];
    #pragma unroll
    for (int n1 = 0; n1 < 8; ++n1) {
        int j = n1 * 256 + t;
        us[n1] = make_float2(bf2f(u0[j]), bf2f(u1[j]));
        v[n1] = us[n1];
        v[n1 + 8] = make_float2(0.f, 0.f);
    }
    fft4096p<-1, true, false>(v, lds, t);
    const float2* kfh = kf + (size_t)h * 2049;
    #pragma unroll
    for (int j2 = 0; j2 < 16; ++j2) {
        int f = t + 256 * j2;
        float2 K;
        if (f <= 2048) K = kfh[f];
        else { float2 q = kfh[4096 - f]; K = make_float2(q.x, -q.y); }
        v[j2] = cmulf(v[j2], K);
    }
    fft4096p<+1, false, true>(v, lds, t);
    float d = Dp[h];
    unsigned short* o0 = ygb + (size_t)((2*bp)   * 256 + h) * 2048;
    unsigned short* o1 = ygb + (size_t)((2*bp+1) * 256 + h) * 2048;
    const float iscl = 1.0f / 4096.0f;
    #pragma unroll
    for (int j2 = 0; j2 < 8; ++j2) {
        int l = t + 256 * j2;
        float y0 = v[j2].x * iscl + d * us[j2].x;
        float y1 = v[j2].y * iscl + d * us[j2].y;
        o0[l] = f2bf(0.5f * y0 * (1.0f + erff(y0 * 0.70710678118654752f)));
        o1[l] = f2bf(0.5f * y1 * (1.0f + erff(y1 * 0.70710678118654752f)));
    }
}

// ---------------- K56: MFMA GEMM + GLU + residual + LayerNorm + store -------
__global__ __launch_bounds__(256, 2) void k56_gemm_glu_ln(const unsigned short* __restrict__ ygb,
        const unsigned short* __restrict__ Wb, const float* __restrict__ bout,
        const unsigned short* __restrict__ ub, const float* __restrict__ gamma,
        const float* __restrict__ beta, float* __restrict__ out)
{
    __shared__ __align__(16) char smem[67584];
    short (*yt)[264] = (short(*)[264])smem;
    short (*Wl)[264] = (short(*)[264])(smem + 33792);
    float (*uS)[65]  = (float(*)[65])smem;
    __shared__ float bo[512];
    __shared__ float gb2[512];
    int b  = blockIdx.y;
    int l0 = blockIdx.x * 64;
    int tid = threadIdx.x;
    int lane = tid & 63, w = tid >> 6;
    int cc = lane & 15, gg = lane >> 4;
    bo[tid] = bout[tid]; bo[tid + 256] = bout[tid + 256];
    gb2[tid] = gamma[tid]; gb2[tid + 256] = beta[tid];
    int li = tid & 63;
    #pragma unroll 4
    for (int it = 0; it < 64; ++it) {
        int hh = (tid >> 6) + it * 4;
        yt[li][hh] = (short)ygb[(size_t)(b * 256 + hh) * 2048 + l0 + li];
    }
    __syncthreads();
    const short* brow = &yt[16 * w + cc][0];
    bf16x8 bfr[8];
    #pragma unroll
    for (int ks = 0; ks < 8; ++ks) bfr[ks] = *(const bf16x8*)(brow + ks * 32 + gg * 8);
    f32x4 acc[32];
    #pragma unroll
    for (int tt = 0; tt < 32; ++tt) acc[tt] = (f32x4){0.f, 0.f, 0.f, 0.f};
    const int fr = tid >> 5, fch = tid & 31;
    bf16x8 pre[8];
    #pragma unroll
    for (int j = 0; j < 8; ++j)
        pre[j] = *(const bf16x8*)(Wb + (size_t)(fr + j * 8) * 256 + fch * 8);
    #pragma unroll
    for (int c = 0; c < 8; ++c) {
        #pragma unroll
        for (int j = 0; j < 8; ++j)
            *(bf16x8*)&Wl[fr + j * 8][fch * 8] = pre[j];
        __syncthreads();
        if (c < 7) {
            #pragma unroll
            for (int j = 0; j < 8; ++j)
                pre[j] = *(const bf16x8*)(Wb + (size_t)((c + 1) * 64 + fr + j * 8) * 256 + fch * 8);
        }
        #pragma unroll
        for (int ks = 0; ks < 8; ++ks) {
            #pragma unroll
            for (int tl = 0; tl < 4; ++tl) {
                bf16x8 afrag = *(const bf16x8*)&Wl[tl * 16 + cc][ks * 32 + gg * 8];
                acc[c * 4 + tl] = __builtin_amdgcn_mfma_f32_16x16x32_bf16(
                    afrag, bfr[ks], acc[c * 4 + tl], 0, 0, 0);
            }
        }
        __syncthreads();
    }
    for (int i = tid; i < 256 * 64; i += 256) {
        int hh = i >> 6, l = i & 63;
        uS[hh][l] = bf2f(ub[(size_t)(b * 256 + hh) * 2048 + l0 + l]);
    }
    __syncthreads();
    int llocal = 16 * w + cc;
    float s = 0.f, q2 = 0.f;
    #pragma unroll
    for (int tt = 0; tt < 16; ++tt) {
        #pragma unroll
        for (int r = 0; r < 4; ++r) {
            int P = tt * 16 + gg * 4 + r;
            float ya = acc[tt][r] + bo[P];
            float gb = acc[tt + 16][r] + bo[256 + P];
            float gv = ya / (1.0f + expf(-gb));
            float val = gv + uS[P][llocal];
            acc[tt][r] = val;
            s += val; q2 += val * val;
        }
    }
    s  += __shfl_xor(s, 16);  s  += __shfl_xor(s, 32);
    q2 += __shfl_xor(q2, 16); q2 += __shfl_xor(q2, 32);
    float mu = s * (1.0f / 256.0f);
    float var = q2 * (1.0f / 256.0f) - mu * mu;
    float rstd = rsqrtf(var + 1e-5f);
    float* ob = out + (size_t)((l0 + llocal) * 16 + b) * 256;
    #pragma unroll
    for (int tt = 0; tt < 16; ++tt) {
        int P0 = tt * 16 + gg * 4;
        float4 o4;
        o4.x = (acc[tt][0] - mu) * rstd * gb2[P0 + 0] + gb2[256 + P0 + 0];
        o4.y = (acc[tt][1] - mu) * rstd * gb2[P0 + 1] + gb2[256 + P0 + 1];
        o4.z = (acc[tt][2] - mu) * rstd * gb2[P0 + 2] + gb2[256 + P0 + 2];
        o4.w = (acc[tt][3] - mu) * rstd * gb2[P0 + 3] + gb2[256 + P0 + 3];
        *(float4*)(ob + P0) = o4;
    }
}

// ---------------- launch ----------------
extern "C" void kernel_launch(void* const* d_in, const int* in_sizes, int n_in,
                              void* d_out, int out_size, void* d_ws, size_t ws_size,
                              hipStream_t stream)
{
    (void)in_sizes; (void)n_in; (void)out_size; (void)ws_size;
    const float* x      = (const float*)d_in[0];
    const float* log_dt = (const float*)d_in[1];
    const float* wlr    = (const float*)d_in[2];
    const float* wim    = (const float*)d_in[3];
    const float* Pre    = (const float*)d_in[4];
    const float* Pim    = (const float*)d_in[5];
    const float* Bre    = (const float*)d_in[6];
    const float* Bim    = (const float*)d_in[7];
    const float* Cre    = (const float*)d_in[8];
    const float* Cim    = (const float*)d_in[9];
    const float* Dp     = (const float*)d_in[10];
    const float* Wout   = (const float*)d_in[11];
    const float* bout   = (const float*)d_in[12];
    const float* gamma  = (const float*)d_in[13];
    const float* beta   = (const float*)d_in[14];

    float* ws  = (float*)d_ws;
    unsigned short* ub  = (unsigned short*)ws;               // 16MB (B,H,L) bf16
    unsigned short* ygb = (unsigned short*)(ws + 4194304);   // 16MB (B,H,L) bf16
    char*  ob  = (char*)d_out;
    float2* kF  = (float2*)(ob);                       // 4,198,400 B
    float2* kfo = (float2*)(ob + 4198400);             // 4,196,352 B
    unsigned short* Wb = (unsigned short*)(ob + 8394752);  // 262,144 B

    k0_convW<<<dim3(512), 256, 0, stream>>>(Wout, Wb);
    k1_kergen<<<dim3(256, 5), 256, 0, stream>>>(log_dt, wlr, wim, Pre, Pim, Bre, Bim, Cre, Cim, kF);
    k2_kernelfft<<<dim3(256), 1024, 0, stream>>>(kF, kfo);
    k3_transpose<<<dim3(64, 32), 256, 0, stream>>>(x, ub);
    k4_conv<<<dim3(2048), 256, 0, stream>>>(ub, kfo, Dp, ygb);
    k56_gemm_glu_ln<<<dim3(32, 16), 256, 0, stream>>>(ygb, Wb, bout, ub, gamma, beta, (float*)d_out);
}

// Round 17
// 107.919 us; speedup vs baseline: 1.2761x; 1.1107x over previous
//
#include <hip/hip_runtime.h>

// S4 (SSSD) layer: L=2048, B=16, H=256, N2=32. Output f32.
// R17: k0+k1+k3 fused into one mega-kernel (block-role by blockIdx range) -
// they are mutually independent; fusion fills the GPU and kills 2 launch
// gaps. k2/k4/k56 unchanged from R16 (bf16 u, reg-FFT k4, MFMA k56).

#define PI_F 3.14159265358979323846f
#define LP(i) ((i) + ((i) >> 4))    // LDS pad for k2's fft_fused

typedef __attribute__((ext_vector_type(8))) short bf16x8;
typedef __attribute__((ext_vector_type(4))) float f32x4;

__device__ __forceinline__ float2 cmulf(float2 a, float2 b) {
    return make_float2(a.x*b.x - a.y*b.y, a.x*b.y + a.y*b.x);
}
__device__ __forceinline__ unsigned short f2bf(float f) {
    unsigned int u = __float_as_uint(f);
    u += 0x7fffu + ((u >> 16) & 1u);
    return (unsigned short)(u >> 16);
}
__device__ __forceinline__ float bf2f(unsigned short us) {
    return __uint_as_float((unsigned int)us << 16);
}

// ------ 16-pt register FFT; HZ: odd post-bitrev inputs zero; HO: outputs 0..7
template<int SGN, bool HZ, bool HO>
__device__ __forceinline__ void fft16(float2 v[16]) {
    float2 tsw;
#define SW(i,j) { tsw = v[i]; v[i] = v[j]; v[j] = tsw; }
    SW(1,8) SW(2,4) SW(3,12) SW(5,10) SW(7,14) SW(11,13)
#undef SW
    const float C8[8] = {1.f, 0.92387953251f, 0.70710678119f, 0.38268343236f,
                         0.f, -0.38268343236f, -0.70710678119f, -0.92387953251f};
    const float S8[8] = {0.f, 0.38268343236f, 0.70710678119f, 0.92387953251f,
                         1.f, 0.92387953251f, 0.70710678119f, 0.38268343236f};
    #pragma unroll
    for (int s = 0; s < 4; ++s) {
        const int Ns = 1 << s;
        #pragma unroll
        for (int j = 0; j < 8; ++j) {
            const int k  = j & (Ns - 1);
            const int i0 = ((j >> s) << (s + 1)) | k;
            const int i1 = i0 + Ns;
            if (HZ && s == 0) { v[i1] = v[i0]; continue; }   // b==0, w==1
            const int ti = k << (3 - s);
            const float cs = C8[ti];
            const float sn = (SGN < 0) ? -S8[ti] : S8[ti];
            float2 a = v[i0], b = v[i1];
            float2 t = make_float2(cs*b.x - sn*b.y, cs*b.y + sn*b.x);
            v[i0] = make_float2(a.x + t.x, a.y + t.y);
            if (!(HO && s == 3)) v[i1] = make_float2(a.x - t.x, a.y - t.y);
        }
    }
}

// ---- apply v[k] *= w^k, k=1..15, w = e^{i*ang}; log-depth power tree -------
__device__ __forceinline__ void tw_apply(float2 v[16], float ang) {
    float sn, cs;
    __sincosf(ang, &sn, &cs);
    float2 W1 = make_float2(cs, sn);
    float2 W2 = cmulf(W1, W1);
    float2 W3 = cmulf(W2, W1);
    float2 W4 = cmulf(W2, W2);
    float2 W5 = cmulf(W4, W1);
    float2 W6 = cmulf(W4, W2);
    float2 W7 = cmulf(W4, W3);
    float2 W8 = cmulf(W4, W4);
    v[1] = cmulf(v[1], W1);   v[2] = cmulf(v[2], W2);
    v[3] = cmulf(v[3], W3);   v[4] = cmulf(v[4], W4);
    v[5] = cmulf(v[5], W5);   v[6] = cmulf(v[6], W6);
    v[7] = cmulf(v[7], W7);   v[8] = cmulf(v[8], W8);
    v[9]  = cmulf(v[9],  cmulf(W8, W1));
    v[10] = cmulf(v[10], cmulf(W8, W2));
    v[11] = cmulf(v[11], cmulf(W8, W3));
    v[12] = cmulf(v[12], cmulf(W8, W4));
    v[13] = cmulf(v[13], cmulf(W8, W5));
    v[14] = cmulf(v[14], cmulf(W8, W6));
    v[15] = cmulf(v[15], cmulf(W8, W7));
}

// ------------- 4096-pt FFT: 3 phases of fft16, 2 LDS transposes -------------
template<int SGN, bool HZ, bool HO>
__device__ __forceinline__ void fft4096p(float2 v[16], float2* lds, int t) {
    fft16<SGN, HZ, false>(v);
    tw_apply(v, (float)SGN * (2.0f * PI_F / 4096.0f) * (float)t);
    __syncthreads();
    #pragma unroll
    for (int k = 0; k < 16; ++k) lds[t * 17 + k] = v[k];
    __syncthreads();
    const int k1 = t & 15, m2 = t >> 4;
    #pragma unroll
    for (int m1 = 0; m1 < 16; ++m1) v[m1] = lds[(m1 * 16 + m2) * 17 + k1];
    fft16<SGN, false, false>(v);
    tw_apply(v, (float)SGN * (2.0f * PI_F / 256.0f) * (float)m2);
    __syncthreads();
    #pragma unroll
    for (int j = 0; j < 16; ++j) lds[m2 * 273 + j * 17 + k1] = v[j];
    __syncthreads();
    #pragma unroll
    for (int m = 0; m < 16; ++m) v[m] = lds[m * 273 + (t >> 4) * 17 + k1];
    fft16<SGN, false, HO>(v);
}

// -------- in-LDS fused double-stage FFT (k2; nthr-parameterized) ------------
template<int SGN>
__device__ __forceinline__ void fft_fused(float2* A, int N, int logN,
                                          int tid, int nthr) {
    __syncthreads();
    for (int j = tid; j < N; j += nthr) {
        int r = (int)(__brev((unsigned)j) >> (32 - logN));
        if (r > j) { float2 t = A[LP(j)]; A[LP(j)] = A[LP(r)]; A[LP(r)] = t; }
    }
    __syncthreads();
    int s = 0;
    if (logN & 1) {
        for (int j = tid; j < (N >> 1); j += nthr) {
            int i0 = 2 * j;
            float2 a = A[LP(i0)], b = A[LP(i0 + 1)];
            A[LP(i0)]     = make_float2(a.x + b.x, a.y + b.y);
            A[LP(i0 + 1)] = make_float2(a.x - b.x, a.y - b.y);
        }
        __syncthreads();
        s = 1;
    }
    for (; s < logN; s += 2) {
        const int Ns = 1 << s;
        for (int g = tid; g < (N >> 2); g += nthr) {
            int k = g & (Ns - 1);
            int base = ((g >> s) << (s + 2)) | k;
            float2 a0 = A[LP(base)];
            float2 a1 = A[LP(base + Ns)];
            float2 a2 = A[LP(base + 2*Ns)];
            float2 a3 = A[LP(base + 3*Ns)];
            float ang1 = (float)SGN * PI_F * (float)k / (float)Ns;
            float sn1, cs1; __sincosf(ang1, &sn1, &cs1);
            float2 t = make_float2(cs1*a1.x - sn1*a1.y, cs1*a1.y + sn1*a1.x);
            float2 b0 = make_float2(a0.x + t.x, a0.y + t.y);
            float2 b1 = make_float2(a0.x - t.x, a0.y - t.y);
            t = make_float2(cs1*a3.x - sn1*a3.y, cs1*a3.y + sn1*a3.x);
            float2 b2 = make_float2(a2.x + t.x, a2.y + t.y);
            float2 b3 = make_float2(a2.x - t.x, a2.y - t.y);
            float ang2 = (float)SGN * PI_F * (float)k / (float)(2 * Ns);
            float sn2, cs2; __sincosf(ang2, &sn2, &cs2);
            t = make_float2(cs2*b2.x - sn2*b2.y, cs2*b2.y + sn2*b2.x);
            A[LP(base)]        = make_float2(b0.x + t.x, b0.y + t.y);
            A[LP(base + 2*Ns)] = make_float2(b0.x - t.x, b0.y - t.y);
            float c2p, s2p;
            if (SGN < 0) { c2p = sn2; s2p = -cs2; } else { c2p = -sn2; s2p = cs2; }
            t = make_float2(c2p*b3.x - s2p*b3.y, c2p*b3.y + s2p*b3.x);
            A[LP(base + Ns)]   = make_float2(b1.x + t.x, b1.y + t.y);
            A[LP(base + 3*Ns)] = make_float2(b1.x - t.x, b1.y - t.y);
        }
        __syncthreads();
    }
}

// ------ K013: fused W-convert + kergen + x-transpose (independent works) ----
// blocks [0,512): convW; [512,1792): kergen (h = idx&255, fchunk = idx>>8);
// [1792,3840): transpose (bx = idx&63 -> p0, by = idx>>6 -> l0).
__global__ __launch_bounds__(256) void k013_fused(const float* __restrict__ W,
        unsigned short* __restrict__ Wb,
        const float* __restrict__ log_dt, const float* __restrict__ wlr,
        const float* __restrict__ wim, const float* __restrict__ Pre,
        const float* __restrict__ Pim, const float* __restrict__ Bre,
        const float* __restrict__ Bim, const float* __restrict__ Cre,
        const float* __restrict__ Cim, float2* __restrict__ kf_out,
        const float* __restrict__ x, unsigned short* __restrict__ ub)
{
    __shared__ __align__(16) char smem[16640];
    int blk = blockIdx.x;
    int tid = threadIdx.x;
    if (blk < 512) {                      // ---- k0: W f32 -> bf16 ----
        int i = blk * 256 + tid;
        Wb[i] = f2bf(W[i]);
        return;
    }
    if (blk < 1792) {                     // ---- k1: NPLR kergen ----
        float4* T0 = (float4*)smem;       // 4 x 32 float4 = 2KB
        float4* T1 = T0 + 32;
        float4* T2 = T1 + 32;
        float4* T3 = T2 + 32;
        int idx = blk - 512;
        int h  = idx & 255;
        int fc = idx >> 8;                // 0..4
        float dt = expf(log_dt[h]);
        if (tid < 32) {
            int i = h * 32 + tid;
            float wre = -expf(wlr[i]) * dt;
            float wi  = wim[i] * dt;
            float2 B  = make_float2(Bre[i], Bim[i]);
            float2 P  = make_float2(Pre[i], Pim[i]);
            float2 C0 = make_float2(Cre[i], Cim[i]);
            float2 C1 = make_float2(Cre[8192 + i], Cim[8192 + i]);
            float2 Pc = make_float2(P.x, -P.y);
            float2 v00 = cmulf(B, C0), v01 = cmulf(B, C1), v02 = cmulf(B, Pc);
            float2 v10 = cmulf(P, C0), v11 = cmulf(P, C1), v12 = cmulf(P, Pc);
            T0[tid] = make_float4(wre, wi, v00.x, v00.y);
            T1[tid] = make_float4(v01.x, v01.y, v02.x, v02.y);
            T2[tid] = make_float4(v10.x, v10.y, v11.x, v11.y);
            T3[tid] = make_float4(v12.x, v12.y, 0.f, 0.f);
        }
        __syncthreads();
        int f = fc * 256 + tid;
        if (f > 1024) return;
        float ang = -(2.0f * PI_F / 2048.0f) * (float)f;
        float sn, cs;
        sincosf(ang, &sn, &cs);
        float2 onep = make_float2(1.0f + cs, sn);
        float invo = __builtin_amdgcn_rcpf(onep.x * onep.x + onep.y * onep.y);
        float2 oinv = make_float2(onep.x * invo, -onep.y * invo);
        float2 z = cmulf(make_float2(2.0f * (1.0f - cs), -2.0f * sn), oinv);
        float2 r00 = {0,0}, r01 = {0,0}, r02 = {0,0};
        float2 r10 = {0,0}, r11 = {0,0}, r12 = {0,0};
        #pragma unroll 4
        for (int n = 0; n < 32; ++n) {
            float4 a  = T0[n];
            float4 bq = T1[n];
            float4 cq = T2[n];
            float4 dq = T3[n];
            float zx  = z.x - a.x;
            float d1y = z.y - a.y;
            float d2y = z.y + a.y;
            float inv1 = __builtin_amdgcn_rcpf(zx * zx + d1y * d1y);
            float inv2 = __builtin_amdgcn_rcpf(zx * zx + d2y * d2y);
            float sx = zx * (inv1 + inv2);
            float dx = zx * (inv1 - inv2);
            float sy = -(d1y * inv1 + d2y * inv2);
            float dy = d1y * inv1 - d2y * inv2;
            r00.x += a.z*sx + a.w*dy;  r00.y += a.z*sy + a.w*dx;
            r01.x += bq.x*sx + bq.y*dy; r01.y += bq.x*sy + bq.y*dx;
            r02.x += bq.z*sx + bq.w*dy; r02.y += bq.z*sy + bq.w*dx;
            r10.x += cq.x*sx + cq.y*dy; r10.y += cq.x*sy + cq.y*dx;
            r11.x += cq.z*sx + cq.w*dy; r11.y += cq.z*sy + cq.w*dx;
            r12.x += dq.x*sx + dq.y*dy; r12.y += dq.x*sy + dq.y*dx;
        }
        r00.x *= dt; r00.y *= dt; r01.x *= dt; r01.y *= dt; r02.x *= dt; r02.y *= dt;
        r10.x *= dt; r10.y *= dt; r11.x *= dt; r11.y *= dt; r12.x *= dt; r12.y *= dt;
        float2 den = make_float2(1.0f + r12.x, r12.y);
        float invd = __builtin_amdgcn_rcpf(den.x * den.x + den.y * den.y);
        float2 idn = make_float2(den.x * invd, -den.y * invd);
        float2 fac = make_float2(2.0f * oinv.x, 2.0f * oinv.y);
        float2 t0 = cmulf(cmulf(r02, r10), idn);
        float2 k0 = cmulf(make_float2(r00.x - t0.x, r00.y - t0.y), fac);
        float2 t1 = cmulf(cmulf(r02, r11), idn);
        float2 k1 = cmulf(make_float2(r01.x - t1.x, r01.y - t1.y), fac);
        kf_out[(size_t)h * 1025 + f]         = k0;
        kf_out[(size_t)(256 + h) * 1025 + f] = k1;
        return;
    }
    // ---- k3: transpose x (2048 x 4096) -> ub bf16 (4096 x 2048) ----
    float (*tile)[65] = (float(*)[65])smem;   // 64 x 65 f32 = 16.64KB
    int idx = blk - 1792;
    int p0 = (idx & 63) * 64;
    int l0 = (idx >> 6) * 64;
    int q = tid & 15, r = tid >> 4;
    #pragma unroll
    for (int k = 0; k < 4; ++k) {
        int row = r + k * 16;
        float4 v = *(const float4*)&x[(size_t)(l0 + row) * 4096 + p0 + q * 4];
        tile[row][q*4+0] = v.x; tile[row][q*4+1] = v.y;
        tile[row][q*4+2] = v.z; tile[row][q*4+3] = v.w;
    }
    __syncthreads();
    #pragma unroll
    for (int g = 0; g < 4; ++g) {
        int ch = tid + 256 * g;
        int p = ch >> 4, c = ch & 15;
        ushort4 pk;
        pk.x = f2bf(tile[c*4+0][p]);
        pk.y = f2bf(tile[c*4+1][p]);
        pk.z = f2bf(tile[c*4+2][p]);
        pk.w = f2bf(tile[c*4+3][p]);
        *(ushort4*)&ub[(size_t)(p0 + p) * 2048 + l0 + c * 4] = pk;
    }
}

// ---------------- K2: packed irfft(ch0,ch1) -> kk -> fft4096 -> kf ----------
__global__ __launch_bounds__(1024) void k2_kernelfft(const float2* __restrict__ kfin,
                                                     float2* __restrict__ kfout)
{
    __shared__ float2 A2[2176];
    __shared__ float2 A4[4352];
    int h = blockIdx.x, tid = threadIdx.x;
    const int NT = 1024;
    const float2* s0 = kfin + (size_t)h * 1025;
    const float2* s1 = kfin + (size_t)(256 + h) * 1025;
    for (int j = tid; j < 2048; j += NT) {
        float2 q0, q1;
        if (j == 0)          { q0 = s0[0];    q0.y = 0.0f; q1 = s1[0];    q1.y = 0.0f; }
        else if (j < 1024)   { q0 = s0[j];                 q1 = s1[j]; }
        else if (j == 1024)  { q0 = s0[1024]; q0.y = 0.0f; q1 = s1[1024]; q1.y = 0.0f; }
        else { float2 t0 = s0[2048 - j], t1 = s1[2048 - j];
               q0 = make_float2(t0.x, -t0.y); q1 = make_float2(t1.x, -t1.y); }
        A2[LP(j)] = make_float2(q0.x - q1.y, q0.y + q1.x);   // E0 + i*E1
    }
    fft_fused<+1>(A2, 2048, 11, tid, NT);
    const float scl = 1.0f / 2048.0f;
    for (int j = tid; j < 2048; j += NT) {
        float2 v = A2[LP(j)];
        A4[LP(j)]        = make_float2(v.x * scl, 0.0f);
        A4[LP(4095 - j)] = make_float2(v.y * scl, 0.0f);
    }
    fft_fused<-1>(A4, 4096, 12, tid, NT);
    for (int F = tid; F <= 2048; F += NT)
        kfout[(size_t)h * 2049 + F] = A4[LP(F)];
}

// ---------------- K4: pair-packed conv via register radix-16 FFT ------------
__global__ __launch_bounds__(256) void k4_conv(const unsigned short* __restrict__ ub,
        const float2* __restrict__ kf, const float* __restrict__ Dp,
        unsigned short* __restrict__ ygb)
{
    __shared__ float2 lds[4366];
    int h  = blockIdx.x & 255;
    int bp = blockIdx.x >> 8;
    int t  = threadIdx.x;
    const unsigned short* u0 = ub + (size_t)((2*bp)   * 256 + h) * 2048;
    const unsigned short* u1 = ub + (size_t)((2*bp+1) * 256 + h) * 2048;
    float2 v[16], us[8];
    #pragma unroll
    for (int n1 = 0; n1 < 8; ++n1) {
        int j = n1 * 256 + t;
        us[n1] = make_float2(bf2f(u0[j]), bf2f(u1[j]));
        v[n1] = us[n1];
        v[n1 + 8] = make_float2(0.f, 0.f);
    }
    fft4096p<-1, true, false>(v, lds, t);
    const float2* kfh = kf + (size_t)h * 2049;
    #pragma unroll
    for (int j2 = 0; j2 < 16; ++j2) {
        int f = t + 256 * j2;
        float2 K;
        if (f <= 2048) K = kfh[f];
        else { float2 q = kfh[4096 - f]; K = make_float2(q.x, -q.y); }
        v[j2] = cmulf(v[j2], K);
    }
    fft4096p<+1, false, true>(v, lds, t);
    float d = Dp[h];
    unsigned short* o0 = ygb + (size_t)((2*bp)   * 256 + h) * 2048;
    unsigned short* o1 = ygb + (size_t)((2*bp+1) * 256 + h) * 2048;
    const float iscl = 1.0f / 4096.0f;
    #pragma unroll
    for (int j2 = 0; j2 < 8; ++j2) {
        int l = t + 256 * j2;
        float y0 = v[j2].x * iscl + d * us[j2].x;
        float y1 = v[j2].y * iscl + d * us[j2].y;
        o0[l] = f2bf(0.5f * y0 * (1.0f + erff(y0 * 0.70710678118654752f)));
        o1[l] = f2bf(0.5f * y1 * (1.0f + erff(y1 * 0.70710678118654752f)));
    }
}

// ---------------- K56: MFMA GEMM + GLU + residual + LayerNorm + store -------
__global__ __launch_bounds__(256, 2) void k56_gemm_glu_ln(const unsigned short* __restrict__ ygb,
        const unsigned short* __restrict__ Wb, const float* __restrict__ bout,
        const unsigned short* __restrict__ ub, const float* __restrict__ gamma,
        const float* __restrict__ beta, float* __restrict__ out)
{
    __shared__ __align__(16) char smem[67584];
    short (*yt)[264] = (short(*)[264])smem;
    short (*Wl)[264] = (short(*)[264])(smem + 33792);
    float (*uS)[65]  = (float(*)[65])smem;
    __shared__ float bo[512];
    __shared__ float gb2[512];
    int b  = blockIdx.y;
    int l0 = blockIdx.x * 64;
    int tid = threadIdx.x;
    int lane = tid & 63, w = tid >> 6;
    int cc = lane & 15, gg = lane >> 4;
    bo[tid] = bout[tid]; bo[tid + 256] = bout[tid + 256];
    gb2[tid] = gamma[tid]; gb2[tid + 256] = beta[tid];
    int li = tid & 63;
    #pragma unroll 4
    for (int it = 0; it < 64; ++it) {
        int hh = (tid >> 6) + it * 4;
        yt[li][hh] = (short)ygb[(size_t)(b * 256 + hh) * 2048 + l0 + li];
    }
    __syncthreads();
    const short* brow = &yt[16 * w + cc][0];
    bf16x8 bfr[8];
    #pragma unroll
    for (int ks = 0; ks < 8; ++ks) bfr[ks] = *(const bf16x8*)(brow + ks * 32 + gg * 8);
    f32x4 acc[32];
    #pragma unroll
    for (int tt = 0; tt < 32; ++tt) acc[tt] = (f32x4){0.f, 0.f, 0.f, 0.f};
    const int fr = tid >> 5, fch = tid & 31;
    bf16x8 pre[8];
    #pragma unroll
    for (int j = 0; j < 8; ++j)
        pre[j] = *(const bf16x8*)(Wb + (size_t)(fr + j * 8) * 256 + fch * 8);
    #pragma unroll
    for (int c = 0; c < 8; ++c) {
        #pragma unroll
        for (int j = 0; j < 8; ++j)
            *(bf16x8*)&Wl[fr + j * 8][fch * 8] = pre[j];
        __syncthreads();
        if (c < 7) {
            #pragma unroll
            for (int j = 0; j < 8; ++j)
                pre[j] = *(const bf16x8*)(Wb + (size_t)((c + 1) * 64 + fr + j * 8) * 256 + fch * 8);
        }
        #pragma unroll
        for (int ks = 0; ks < 8; ++ks) {
            #pragma unroll
            for (int tl = 0; tl < 4; ++tl) {
                bf16x8 afrag = *(const bf16x8*)&Wl[tl * 16 + cc][ks * 32 + gg * 8];
                acc[c * 4 + tl] = __builtin_amdgcn_mfma_f32_16x16x32_bf16(
                    afrag, bfr[ks], acc[c * 4 + tl], 0, 0, 0);
            }
        }
        __syncthreads();
    }
    for (int i = tid; i < 256 * 64; i += 256) {
        int hh = i >> 6, l = i & 63;
        uS[hh][l] = bf2f(ub[(size_t)(b * 256 + hh) * 2048 + l0 + l]);
    }
    __syncthreads();
    int llocal = 16 * w + cc;
    float s = 0.f, q2 = 0.f;
    #pragma unroll
    for (int tt = 0; tt < 16; ++tt) {
        #pragma unroll
        for (int r = 0; r < 4; ++r) {
            int P = tt * 16 + gg * 4 + r;
            float ya = acc[tt][r] + bo[P];
            float gb = acc[tt + 16][r] + bo[256 + P];
            float gv = ya / (1.0f + expf(-gb));
            float val = gv + uS[P][llocal];
            acc[tt][r] = val;
            s += val; q2 += val * val;
        }
    }
    s  += __shfl_xor(s, 16);  s  += __shfl_xor(s, 32);
    q2 += __shfl_xor(q2, 16); q2 += __shfl_xor(q2, 32);
    float mu = s * (1.0f / 256.0f);
    float var = q2 * (1.0f / 256.0f) - mu * mu;
    float rstd = rsqrtf(var + 1e-5f);
    float* ob = out + (size_t)((l0 + llocal) * 16 + b) * 256;
    #pragma unroll
    for (int tt = 0; tt < 16; ++tt) {
        int P0 = tt * 16 + gg * 4;
        float4 o4;
        o4.x = (acc[tt][0] - mu) * rstd * gb2[P0 + 0] + gb2[256 + P0 + 0];
        o4.y = (acc[tt][1] - mu) * rstd * gb2[P0 + 1] + gb2[256 + P0 + 1];
        o4.z = (acc[tt][2] - mu) * rstd * gb2[P0 + 2] + gb2[256 + P0 + 2];
        o4.w = (acc[tt][3] - mu) * rstd * gb2[P0 + 3] + gb2[256 + P0 + 3];
        *(float4*)(ob + P0) = o4;
    }
}

// ---------------- launch ----------------
extern "C" void kernel_launch(void* const* d_in, const int* in_sizes, int n_in,
                              void* d_out, int out_size, void* d_ws, size_t ws_size,
                              hipStream_t stream)
{
    (void)in_sizes; (void)n_in; (void)out_size; (void)ws_size;
    const float* x      = (const float*)d_in[0];
    const float* log_dt = (const float*)d_in[1];
    const float* wlr    = (const float*)d_in[2];
    const float* wim    = (const float*)d_in[3];
    const float* Pre    = (const float*)d_in[4];
    const float* Pim    = (const float*)d_in[5];
    const float* Bre    = (const float*)d_in[6];
    const float* Bim    = (const float*)d_in[7];
    const float* Cre    = (const float*)d_in[8];
    const float* Cim    = (const float*)d_in[9];
    const float* Dp     = (const float*)d_in[10];
    const float* Wout   = (const float*)d_in[11];
    const float* bout   = (const float*)d_in[12];
    const float* gamma  = (const float*)d_in[13];
    const float* beta   = (const float*)d_in[14];

    float* ws  = (float*)d_ws;
    unsigned short* ub  = (unsigned short*)ws;               // 16MB (B,H,L) bf16
    unsigned short* ygb = (unsigned short*)(ws + 4194304);   // 16MB (B,H,L) bf16
    char*  ob  = (char*)d_out;
    float2* kF  = (float2*)(ob);                       // 4,198,400 B
    float2* kfo = (float2*)(ob + 4198400);             // 4,196,352 B
    unsigned short* Wb = (unsigned short*)(ob + 8394752);  // 262,144 B

    k013_fused<<<dim3(3840), 256, 0, stream>>>(Wout, Wb, log_dt, wlr, wim,
        Pre, Pim, Bre, Bim, Cre, Cim, kF, x, ub);
    k2_kernelfft<<<dim3(256), 1024, 0, stream>>>(kF, kfo);
    k4_conv<<<dim3(2048), 256, 0, stream>>>(ub, kfo, Dp, ygb);
    k56_gemm_glu_ln<<<dim3(32, 16), 256, 0, stream>>>(ygb, Wb, bout, ub, gamma, beta, (float*)d_out);
}